// Round 1
// baseline (305.339 us; speedup 1.0000x reference)
//
#include <hip/hip_runtime.h>

typedef __attribute__((ext_vector_type(8))) __bf16 bf16x8;
typedef __attribute__((ext_vector_type(8))) unsigned short ushort8;
typedef __attribute__((ext_vector_type(4))) float f32x4;
typedef unsigned short ushort_t;

#define MFMA_BF16(A,B,C) __builtin_amdgcn_mfma_f32_16x16x32_bf16(A,B,C,0,0,0)

#define T_SEQ 4096
#define DM 512
#define HD_ 64
#define NH_ 8

__device__ __forceinline__ unsigned short f2b(float f){
    unsigned int u = __builtin_bit_cast(unsigned int, f);
    u += 0x7FFFu + ((u >> 16) & 1u);   // round-to-nearest-even
    return (unsigned short)(u >> 16);
}

__device__ __forceinline__ void gload_lds16(const void* g, void* l){
    __builtin_amdgcn_global_load_lds((const __attribute__((address_space(1))) void*)g,
                                     (__attribute__((address_space(3))) void*)l, 16, 0, 0);
}

// ---------------- GEMM: C[M,512] = A[M,512] @ W[512,512]^T + bias ----------------
// 128x128 tile, BK=64, 256 threads (4 waves, each 64x64). A,W are f32, converted
// to bf16 during reg-staging into XOR-swizzled LDS (chunk ^= row&7, 16B chunks).
template<int OUT_BF16>
__device__ __forceinline__ void gemm_body(const float* __restrict__ A, const float* __restrict__ W,
                                          const float* __restrict__ bias, void* __restrict__ Cout,
                                          int m0, int n0)
{
    constexpr int K = 512, N = 512;
    __shared__ ushort_t As[128*64];
    __shared__ ushort_t Bs[128*64];

    const int tid  = threadIdx.x;
    const int lane = tid & 63;
    const int w    = tid >> 6;
    const int g    = lane >> 4;
    const int c16  = lane & 15;
    const int wm   = w >> 1, wn = w & 1;

    f32x4 acc[4][4];
#pragma unroll
    for (int i=0;i<4;i++)
#pragma unroll
        for (int j=0;j<4;j++) acc[i][j] = (f32x4){0.f,0.f,0.f,0.f};

#pragma unroll 1
    for (int kt=0; kt<K/64; kt++){
        __syncthreads();
        // stage A and B tiles: 128 rows x 64 k each, 1024 chunks of 8 elems
#pragma unroll
        for (int j=0;j<4;j++){
            int cid = j*256 + tid;
            int row = cid >> 3, ch = cid & 7;
            const float* srcA = A + (size_t)(m0+row)*K + kt*64 + ch*8;
            const float* srcB = W + (size_t)(n0+row)*K + kt*64 + ch*8;
            float4 a0 = *(const float4*)srcA;
            float4 a1 = *(const float4*)(srcA+4);
            float4 b0 = *(const float4*)srcB;
            float4 b1 = *(const float4*)(srcB+4);
            ushort8 va, vb;
            va[0]=f2b(a0.x); va[1]=f2b(a0.y); va[2]=f2b(a0.z); va[3]=f2b(a0.w);
            va[4]=f2b(a1.x); va[5]=f2b(a1.y); va[6]=f2b(a1.z); va[7]=f2b(a1.w);
            vb[0]=f2b(b0.x); vb[1]=f2b(b0.y); vb[2]=f2b(b0.z); vb[3]=f2b(b0.w);
            vb[4]=f2b(b1.x); vb[5]=f2b(b1.y); vb[6]=f2b(b1.z); vb[7]=f2b(b1.w);
            int dst = row*64 + ((ch ^ (row & 7))<<3);
            *(ushort8*)&As[dst] = va;
            *(ushort8*)&Bs[dst] = vb;
        }
        __syncthreads();
#pragma unroll
        for (int ks=0; ks<2; ks++){
            bf16x8 af[4], bfr[4];
#pragma unroll
            for (int f=0; f<4; f++){
                int rowa = wm*64 + f*16 + c16;
                af[f]  = *(const bf16x8*)&As[rowa*64 + (((ks*4+g) ^ (rowa&7))<<3)];
                int rowb = wn*64 + f*16 + c16;
                bfr[f] = *(const bf16x8*)&Bs[rowb*64 + (((ks*4+g) ^ (rowb&7))<<3)];
            }
#pragma unroll
            for (int fm=0; fm<4; fm++)
#pragma unroll
                for (int fn=0; fn<4; fn++)
                    acc[fm][fn] = MFMA_BF16(af[fm], bfr[fn], acc[fm][fn]);
        }
    }
    // epilogue: C/D layout col = lane&15, row = (lane>>4)*4 + reg
#pragma unroll
    for (int fm=0; fm<4; fm++)
#pragma unroll
        for (int fn=0; fn<4; fn++){
            int col = n0 + wn*64 + fn*16 + c16;
            float bv = bias[col];
#pragma unroll
            for (int r=0; r<4; r++){
                int rowm = m0 + wm*64 + fm*16 + g*4 + r;
                float vv = acc[fm][fn][r] + bv;
                if (OUT_BF16) ((ushort_t*)Cout)[(size_t)rowm*N + col] = f2b(vv);
                else          ((float*)Cout)[(size_t)rowm*N + col]   = vv;
            }
        }
}

__global__ __launch_bounds__(256,2) void gemm_qkv_kernel(
    const float* __restrict__ q, const float* __restrict__ k, const float* __restrict__ v,
    const float* __restrict__ Wq, const float* __restrict__ bq,
    const float* __restrict__ Wk, const float* __restrict__ bk,
    const float* __restrict__ Wv, const float* __restrict__ bv,
    ushort_t* __restrict__ QKVp)
{
    int z = blockIdx.z;
    const float* A  = (z==0) ? q  : (z==1 ? k  : v);
    const float* W  = (z==0) ? Wq : (z==1 ? Wk : Wv);
    const float* bb = (z==0) ? bq : (z==1 ? bk : bv);
    ushort_t* C = QKVp + (size_t)z * (size_t)(2*T_SEQ) * DM;
    gemm_body<1>(A, W, bb, C, blockIdx.x*128, blockIdx.y*128);
}

__global__ __launch_bounds__(256,2) void gemm_out_kernel(
    const float* __restrict__ O, const float* __restrict__ Wo,
    const float* __restrict__ bo, float* __restrict__ out)
{
    gemm_body<0>(O, Wo, bo, out, blockIdx.x*128, blockIdx.y*128);
}

// ---------------- Flash attention with stoichiometric bias ----------------
// block = 256 thr (4 waves); 128 q rows per block (wave = 32 rows); KV tile = 64.
__global__ __launch_bounds__(256,2) void flash_kernel(
    const ushort_t* __restrict__ Qp, const ushort_t* __restrict__ Kp, const ushort_t* __restrict__ Vp,
    const float* __restrict__ frac, const float* __restrict__ alphap, const float* __restrict__ alphan,
    float* __restrict__ O)
{
    // XCD-aware mapping: all q-tiles of a (b,h) land on one XCD (K/V fits its L2)
    int i    = blockIdx.x;
    int slot = i & 7;
    int seq  = i >> 3;
    int bh   = slot*2 + (seq >> 5);
    int qt   = seq & 31;
    int b    = bh >> 3, h = bh & 7;
    int q0   = qt * 128;

    const int tid  = threadIdx.x;
    const int w    = tid >> 6;
    const int lane = tid & 63;
    const int g    = lane >> 4;
    const int c16  = lane & 15;

    __shared__ ushort_t Ks[64*64];     // [kv][d], chunk-swizzled by row&7
    __shared__ ushort_t VT[64*64];     // [d][kv], chunk-swizzled by d&7
    __shared__ ushort_t PW[4][32*64];  // per-wave P, chunk-swizzled
    __shared__ float    FK[64];

    const ushort_t* Qbase = Qp + (size_t)(b*T_SEQ)*DM + h*HD_;
    const ushort_t* Kbase = Kp + (size_t)(b*T_SEQ)*DM + h*HD_;
    const ushort_t* Vbase = Vp + (size_t)(b*T_SEQ)*DM + h*HD_;
    const float*    fr    = frac + b*T_SEQ;

    const float ap = alphap[h], an = alphan[h];
    const int qrow_base = q0 + w*32;

    // Q fragments in registers (A-operand: row = lane&15, k = (lane>>4)*8+e)
    bf16x8 qa[2][2];
#pragma unroll
    for (int fm=0; fm<2; fm++)
#pragma unroll
        for (int ks=0; ks<2; ks++){
            int qr = qrow_base + fm*16 + c16;
            qa[fm][ks] = *(const bf16x8*)(Qbase + (size_t)qr*DM + ks*32 + g*8);
        }
    float fi[2][4];
#pragma unroll
    for (int fm=0; fm<2; fm++)
#pragma unroll
        for (int r=0; r<4; r++)
            fi[fm][r] = fr[qrow_base + fm*16 + g*4 + r];

    float m[2][4], lsum[2][4];
    f32x4 acc[2][4];
#pragma unroll
    for (int fm=0; fm<2; fm++)
#pragma unroll
        for (int r=0; r<4; r++){ m[fm][r] = -1e30f; lsum[fm][r] = 0.f; }
#pragma unroll
    for (int fm=0; fm<2; fm++)
#pragma unroll
        for (int dt=0; dt<4; dt++) acc[fm][dt] = (f32x4){0.f,0.f,0.f,0.f};

#pragma unroll 1
    for (int kt=0; kt<T_SEQ/64; kt++){
        int kv0 = kt*64;
        __syncthreads();
        // --- stage K via global_load_lds (linear dest, pre-swizzled source) ---
#pragma unroll
        for (int j=0; j<2; j++){
            int base16 = (j*4 + w)*64;           // wave-round chunk base
            int idx16  = base16 + lane;
            int row = idx16 >> 3, cc = idx16 & 7;
            int cs  = cc ^ (row & 7);
            gload_lds16(Kbase + (size_t)(kv0+row)*DM + cs*8, &Ks[base16*8]);
        }
        // --- stage V transposed (reg-staged): VT[d][kv] swizzled ---
        {
            int kvr = tid & 63, d0 = (tid >> 6)*16;
            const ushort_t* vp = Vbase + (size_t)(kv0+kvr)*DM + d0;
            ushort8 v0 = *(const ushort8*)vp;
            ushort8 v1 = *(const ushort8*)(vp + 8);
            int cch = kvr >> 3, ce = kvr & 7;
#pragma unroll
            for (int jj=0; jj<8; jj++){
                int d  = d0 + jj;
                VT[d*64  + (((cch ^ (d&7))<<3) | ce)] = v0[jj];
                int d2 = d0 + 8 + jj;
                VT[d2*64 + (((cch ^ (d2&7))<<3) | ce)] = v1[jj];
            }
            if (tid < 64) FK[tid] = fr[kv0 + tid];
        }
        __syncthreads();

        // --- S = Q K^T ---
        f32x4 s[2][4];
#pragma unroll
        for (int fm=0; fm<2; fm++)
#pragma unroll
            for (int n=0; n<4; n++) s[fm][n] = (f32x4){0.f,0.f,0.f,0.f};
#pragma unroll
        for (int n=0; n<4; n++){
#pragma unroll
            for (int ks=0; ks<2; ks++){
                int row = n*16 + c16;            // kv row (B-operand col)
                int ch  = (ks*4 + g) ^ (row & 7);
                bf16x8 kb = *(const bf16x8*)&Ks[row*64 + (ch<<3)];
#pragma unroll
                for (int fm=0; fm<2; fm++)
                    s[fm][n] = MFMA_BF16(qa[fm][ks], kb, s[fm][n]);
            }
        }

        // --- bias + online softmax (in-place in s) ---
        float fjv[4];
#pragma unroll
        for (int n=0; n<4; n++) fjv[n] = FK[n*16 + c16];
#pragma unroll
        for (int fm=0; fm<2; fm++){
#pragma unroll
            for (int n=0; n<4; n++)
#pragma unroll
                for (int r=0; r<4; r++){
                    float dd  = fjv[n] - fi[fm][r];
                    float bia = (dd > 0.f) ? ap*dd : an*dd;
                    s[fm][n][r] = s[fm][n][r]*0.125f + bia;
                }
#pragma unroll
            for (int r=0; r<4; r++){
                float mx = fmaxf(fmaxf(s[fm][0][r], s[fm][1][r]), fmaxf(s[fm][2][r], s[fm][3][r]));
#pragma unroll
                for (int msk=1; msk<16; msk<<=1) mx = fmaxf(mx, __shfl_xor(mx, msk));
                float mnew = fmaxf(m[fm][r], mx);
                float fac  = __expf(m[fm][r] - mnew);
                m[fm][r] = mnew;
                float rs = 0.f;
#pragma unroll
                for (int n=0; n<4; n++){
                    float p = __expf(s[fm][n][r] - mnew);
                    s[fm][n][r] = p;
                    rs += p;
                }
#pragma unroll
                for (int msk=1; msk<16; msk<<=1) rs += __shfl_xor(rs, msk);
                lsum[fm][r] = lsum[fm][r]*fac + rs;
#pragma unroll
                for (int dt=0; dt<4; dt++) acc[fm][dt][r] *= fac;
            }
        }

        // --- P -> LDS (wave-private, swizzled), then PV ---
#pragma unroll
        for (int fm=0; fm<2; fm++)
#pragma unroll
            for (int n=0; n<4; n++)
#pragma unroll
                for (int r=0; r<4; r++){
                    int row = fm*16 + g*4 + r;
                    int col = n*16 + c16;
                    PW[w][row*64 + (((col>>3) ^ (row&7))<<3) + (col&7)] = f2b(s[fm][n][r]);
                }
#pragma unroll
        for (int ks=0; ks<2; ks++){
            bf16x8 pa[2];
#pragma unroll
            for (int fm=0; fm<2; fm++){
                int row = fm*16 + c16;
                pa[fm] = *(const bf16x8*)&PW[w][row*64 + ((((ks*4+g) ^ (row&7)))<<3)];
            }
#pragma unroll
            for (int dt=0; dt<4; dt++){
                int vr = dt*16 + c16;
                bf16x8 vb = *(const bf16x8*)&VT[vr*64 + ((((ks*4+g) ^ (vr&7)))<<3)];
#pragma unroll
                for (int fm=0; fm<2; fm++)
                    acc[fm][dt] = MFMA_BF16(pa[fm], vb, acc[fm][dt]);
            }
        }
    }

    // --- epilogue: O[b, q, h*64+d] = acc / lsum  (f32) ---
#pragma unroll
    for (int fm=0; fm<2; fm++)
#pragma unroll
        for (int dt=0; dt<4; dt++)
#pragma unroll
            for (int r=0; r<4; r++){
                int qr = qrow_base + fm*16 + g*4 + r;
                O[(size_t)(b*T_SEQ + qr)*DM + h*HD_ + dt*16 + c16] = acc[fm][dt][r] / lsum[fm][r];
            }
}

// ---------------- launcher ----------------
extern "C" void kernel_launch(void* const* d_in, const int* in_sizes, int n_in,
                              void* d_out, int out_size, void* d_ws, size_t ws_size,
                              hipStream_t stream)
{
    const float* q  = (const float*)d_in[0];
    const float* k  = (const float*)d_in[1];
    const float* v  = (const float*)d_in[2];
    const float* fr = (const float*)d_in[3];
    const float* Wq = (const float*)d_in[4];
    const float* bq = (const float*)d_in[5];
    const float* Wk = (const float*)d_in[6];
    const float* bk = (const float*)d_in[7];
    const float* Wv = (const float*)d_in[8];
    const float* bv = (const float*)d_in[9];
    const float* Wo = (const float*)d_in[10];
    const float* bo = (const float*)d_in[11];
    const float* ap = (const float*)d_in[12];
    const float* an = (const float*)d_in[13];

    const size_t MT = (size_t)(2*T_SEQ) * DM;      // 4M elements
    ushort_t* QKVp = (ushort_t*)d_ws;              // 3 * 8MB bf16
    float*    O    = (float*)((char*)d_ws + 3*MT*sizeof(ushort_t)); // 16MB f32

    dim3 gq(64, 4, 3);
    gemm_qkv_kernel<<<gq, 256, 0, stream>>>(q,k,v,Wq,bq,Wk,bk,Wv,bv,QKVp);

    flash_kernel<<<512, 256, 0, stream>>>(QKVp, QKVp + MT, QKVp + 2*MT, fr, ap, an, O);

    dim3 go(64, 4, 1);
    gemm_out_kernel<<<go, 256, 0, stream>>>(O, Wo, bo, (float*)d_out);
}

// Round 2
// 266.371 us; speedup vs baseline: 1.1463x; 1.1463x over previous
//
#include <hip/hip_runtime.h>

typedef __attribute__((ext_vector_type(8))) __bf16 bf16x8;
typedef __attribute__((ext_vector_type(8))) unsigned short ushort8;
typedef __attribute__((ext_vector_type(4))) float f32x4;
typedef unsigned short ushort_t;

#define MFMA_BF16(A,B,C) __builtin_amdgcn_mfma_f32_16x16x32_bf16(A,B,C,0,0,0)

#define T_SEQ 4096
#define DM 512
#define HD_ 64
#define NH_ 8

__device__ __forceinline__ unsigned short f2b(float f){
    unsigned int u = __builtin_bit_cast(unsigned int, f);
    u += 0x7FFFu + ((u >> 16) & 1u);   // round-to-nearest-even
    return (unsigned short)(u >> 16);
}

__device__ __forceinline__ void gload_lds16(const void* g, void* l){
    __builtin_amdgcn_global_load_lds((const __attribute__((address_space(1))) void*)g,
                                     (__attribute__((address_space(3))) void*)l, 16, 0, 0);
}

// ---------------- GEMM: C[M,512] = A[M,512] @ W[512,512]^T + bias ----------------
template<int OUT_BF16>
__device__ __forceinline__ void gemm_body(const float* __restrict__ A, const float* __restrict__ W,
                                          const float* __restrict__ bias, void* __restrict__ Cout,
                                          int m0, int n0)
{
    constexpr int K = 512, N = 512;
    __shared__ ushort_t As[128*64];
    __shared__ ushort_t Bs[128*64];

    const int tid  = threadIdx.x;
    const int lane = tid & 63;
    const int w    = tid >> 6;
    const int g    = lane >> 4;
    const int c16  = lane & 15;
    const int wm   = w >> 1, wn = w & 1;

    f32x4 acc[4][4];
#pragma unroll
    for (int i=0;i<4;i++)
#pragma unroll
        for (int j=0;j<4;j++) acc[i][j] = (f32x4){0.f,0.f,0.f,0.f};

#pragma unroll 1
    for (int kt=0; kt<K/64; kt++){
        __syncthreads();
#pragma unroll
        for (int j=0;j<4;j++){
            int cid = j*256 + tid;
            int row = cid >> 3, ch = cid & 7;
            const float* srcA = A + (size_t)(m0+row)*K + kt*64 + ch*8;
            const float* srcB = W + (size_t)(n0+row)*K + kt*64 + ch*8;
            float4 a0 = *(const float4*)srcA;
            float4 a1 = *(const float4*)(srcA+4);
            float4 b0 = *(const float4*)srcB;
            float4 b1 = *(const float4*)(srcB+4);
            ushort8 va, vb;
            va[0]=f2b(a0.x); va[1]=f2b(a0.y); va[2]=f2b(a0.z); va[3]=f2b(a0.w);
            va[4]=f2b(a1.x); va[5]=f2b(a1.y); va[6]=f2b(a1.z); va[7]=f2b(a1.w);
            vb[0]=f2b(b0.x); vb[1]=f2b(b0.y); vb[2]=f2b(b0.z); vb[3]=f2b(b0.w);
            vb[4]=f2b(b1.x); vb[5]=f2b(b1.y); vb[6]=f2b(b1.z); vb[7]=f2b(b1.w);
            int dst = row*64 + ((ch ^ (row & 7))<<3);
            *(ushort8*)&As[dst] = va;
            *(ushort8*)&Bs[dst] = vb;
        }
        __syncthreads();
#pragma unroll
        for (int ks=0; ks<2; ks++){
            bf16x8 af[4], bfr[4];
#pragma unroll
            for (int f=0; f<4; f++){
                int rowa = wm*64 + f*16 + c16;
                af[f]  = *(const bf16x8*)&As[rowa*64 + (((ks*4+g) ^ (rowa&7))<<3)];
                int rowb = wn*64 + f*16 + c16;
                bfr[f] = *(const bf16x8*)&Bs[rowb*64 + (((ks*4+g) ^ (rowb&7))<<3)];
            }
#pragma unroll
            for (int fm=0; fm<4; fm++)
#pragma unroll
                for (int fn=0; fn<4; fn++)
                    acc[fm][fn] = MFMA_BF16(af[fm], bfr[fn], acc[fm][fn]);
        }
    }
#pragma unroll
    for (int fm=0; fm<4; fm++)
#pragma unroll
        for (int fn=0; fn<4; fn++){
            int col = n0 + wn*64 + fn*16 + c16;
            float bv = bias[col];
#pragma unroll
            for (int r=0; r<4; r++){
                int rowm = m0 + wm*64 + fm*16 + g*4 + r;
                float vv = acc[fm][fn][r] + bv;
                if (OUT_BF16) ((ushort_t*)Cout)[(size_t)rowm*N + col] = f2b(vv);
                else          ((float*)Cout)[(size_t)rowm*N + col]   = vv;
            }
        }
}

__global__ __launch_bounds__(256,2) void gemm_qkv_kernel(
    const float* __restrict__ q, const float* __restrict__ k, const float* __restrict__ v,
    const float* __restrict__ Wq, const float* __restrict__ bq,
    const float* __restrict__ Wk, const float* __restrict__ bk,
    const float* __restrict__ Wv, const float* __restrict__ bv,
    ushort_t* __restrict__ QKVp)
{
    int z = blockIdx.z;
    const float* A  = (z==0) ? q  : (z==1 ? k  : v);
    const float* W  = (z==0) ? Wq : (z==1 ? Wk : Wv);
    const float* bb = (z==0) ? bq : (z==1 ? bk : bv);
    ushort_t* C = QKVp + (size_t)z * (size_t)(2*T_SEQ) * DM;
    gemm_body<1>(A, W, bb, C, blockIdx.x*128, blockIdx.y*128);
}

__global__ __launch_bounds__(256,2) void gemm_out_kernel(
    const float* __restrict__ O, const float* __restrict__ Wo,
    const float* __restrict__ bo, float* __restrict__ out)
{
    gemm_body<0>(O, Wo, bo, out, blockIdx.x*128, blockIdx.y*128);
}

// ---------------- V transpose: Vt[bh][d][t] <- V[b*T+t][h*64+d] ----------------
__global__ __launch_bounds__(256) void vtrans_kernel(const ushort_t* __restrict__ Vp,
                                                     ushort_t* __restrict__ Vt)
{
    int blk = blockIdx.x;            // 16 bh * 64 t-tiles = 1024
    int bh  = blk >> 6;
    int t0  = (blk & 63) << 6;
    int b = bh >> 3, h = bh & 7;
    __shared__ ushort_t tile[64][65];
    const int tid = threadIdx.x;
    const ushort_t* src = Vp + (size_t)(b*T_SEQ + t0)*DM + h*HD_;
#pragma unroll
    for (int p=0; p<2; p++){
        int row = (tid>>3) + p*32;
        int c8  = (tid&7)*8;
        ushort8 v = *(const ushort8*)(src + (size_t)row*DM + c8);
#pragma unroll
        for (int j=0;j<8;j++) tile[row][c8+j] = v[j];
    }
    __syncthreads();
    ushort_t* dst = Vt + (size_t)bh*HD_*T_SEQ + t0;
#pragma unroll
    for (int p=0; p<2; p++){
        int d  = (tid>>3) + p*32;
        int c8 = (tid&7)*8;
        ushort8 v;
#pragma unroll
        for (int j=0;j<8;j++) v[j] = tile[c8+j][d];
        *(ushort8*)(dst + (size_t)d*T_SEQ + c8) = v;
    }
}

// ---------------- Flash attention with stoichiometric bias ----------------
// 256 thr (4 waves), 64 q rows/block (wave = 16 rows), KV tile 64, dbuf K/V^T.
__global__ __launch_bounds__(256,4) void flash_kernel(
    const ushort_t* __restrict__ Qp, const ushort_t* __restrict__ Kp, const ushort_t* __restrict__ Vt,
    const float* __restrict__ frac, const float* __restrict__ alphap, const float* __restrict__ alphan,
    float* __restrict__ O)
{
    // XCD-aware: 2 bh per XCD; their K/V (2 MB) live in that XCD's L2
    int i    = blockIdx.x;
    int slot = i & 7;
    int seq  = i >> 3;
    int bh   = slot*2 + (seq >> 6);
    int qt   = seq & 63;
    int b    = bh >> 3, h = bh & 7;
    int q0   = qt * 64;

    const int tid  = threadIdx.x;
    const int w    = tid >> 6;
    const int lane = tid & 63;
    const int g    = lane >> 4;
    const int c16  = lane & 15;

    __shared__ ushort_t Ks [2][64*64];   // [kv][d], chunk ^ (row&7)
    __shared__ ushort_t VTs[2][64*64];   // [d][kv], chunk ^ (row&7)
    __shared__ ushort_t PW [4][16*64];   // per-wave P

    const ushort_t* Qbase = Qp + (size_t)(b*T_SEQ)*DM + h*HD_;
    const ushort_t* Kbase = Kp + (size_t)(b*T_SEQ)*DM + h*HD_;
    const ushort_t* Vtb   = Vt + (size_t)bh*HD_*T_SEQ;
    const float*    fr    = frac + b*T_SEQ;
    const float ap = alphap[h], an = alphan[h];
    const int qrow = q0 + w*16;

    // Q fragments (A-operand: row = c16, k = g*8+e + ks*32)
    bf16x8 qa[2];
#pragma unroll
    for (int ks=0; ks<2; ks++)
        qa[ks] = *(const bf16x8*)(Qbase + (size_t)(qrow + c16)*DM + ks*32 + g*8);
    float fi[4];
#pragma unroll
    for (int r=0; r<4; r++) fi[r] = fr[qrow + g*4 + r];

    float m[4], lsum[4];
    f32x4 acc[4];
#pragma unroll
    for (int r=0; r<4; r++){ m[r] = -1e30f; lsum[r] = 0.f; }
#pragma unroll
    for (int dt=0; dt<4; dt++) acc[dt] = (f32x4){0.f,0.f,0.f,0.f};

#define STAGE(BUF, KV0)                                                          \
    {                                                                            \
        _Pragma("unroll")                                                        \
        for (int j=0;j<2;j++){                                                   \
            int cb  = (j*4 + w)*64;                                              \
            int idx = cb + lane;                                                 \
            int row = idx >> 3, cc = idx & 7;                                    \
            int cs  = cc ^ (row & 7);                                            \
            gload_lds16(Kbase + (size_t)((KV0)+row)*DM + cs*8, &Ks[BUF][cb*8]);  \
            gload_lds16(Vtb + (size_t)row*T_SEQ + (KV0) + cs*8, &VTs[BUF][cb*8]);\
        }                                                                        \
    }

    STAGE(0, 0);
    asm volatile("s_waitcnt vmcnt(0)" ::: "memory");
    __syncthreads();

    int buf = 0;
#pragma unroll 1
    for (int kt=0; kt<T_SEQ/64; kt++){
        int kv0 = kt*64;
        if (kt+1 < T_SEQ/64) STAGE(buf^1, kv0+64);

        float fjv[4];
#pragma unroll
        for (int n=0; n<4; n++) fjv[n] = fr[kv0 + n*16 + c16];

        // --- S = Q K^T ---
        f32x4 s[4];
#pragma unroll
        for (int n=0; n<4; n++) s[n] = (f32x4){0.f,0.f,0.f,0.f};
        __builtin_amdgcn_s_setprio(1);
#pragma unroll
        for (int n=0; n<4; n++){
#pragma unroll
            for (int ks=0; ks<2; ks++){
                int row = n*16 + c16;
                bf16x8 kb = *(const bf16x8*)&Ks[buf][row*64 + (((ks*4+g) ^ (row&7))<<3)];
                s[n] = MFMA_BF16(qa[ks], kb, s[n]);
            }
        }
        __builtin_amdgcn_s_setprio(0);

        // --- bias + online softmax ---
#pragma unroll
        for (int n=0; n<4; n++)
#pragma unroll
            for (int r=0; r<4; r++){
                float dd  = fjv[n] - fi[r];
                float bia = (dd > 0.f) ? ap*dd : an*dd;
                s[n][r] = s[n][r]*0.125f + bia;
            }
#pragma unroll
        for (int r=0; r<4; r++){
            float mx = fmaxf(fmaxf(s[0][r], s[1][r]), fmaxf(s[2][r], s[3][r]));
#pragma unroll
            for (int msk=1; msk<16; msk<<=1) mx = fmaxf(mx, __shfl_xor(mx, msk));
            float mnew = fmaxf(m[r], mx);
            float fac  = __expf(m[r] - mnew);
            m[r] = mnew;
            float rs = 0.f;
#pragma unroll
            for (int n=0; n<4; n++){
                float p = __expf(s[n][r] - mnew);
                s[n][r] = p;
                rs += p;
            }
#pragma unroll
            for (int msk=1; msk<16; msk<<=1) rs += __shfl_xor(rs, msk);
            lsum[r] = lsum[r]*fac + rs;
#pragma unroll
            for (int dt=0; dt<4; dt++) acc[dt][r] *= fac;
        }

        // --- P -> LDS (wave-private), then PV ---
#pragma unroll
        for (int n=0; n<4; n++)
#pragma unroll
            for (int r=0; r<4; r++){
                int row = g*4 + r;
                int col = n*16 + c16;
                PW[w][row*64 + (((col>>3) ^ (row&7))<<3) + (col&7)] = f2b(s[n][r]);
            }
        __builtin_amdgcn_s_setprio(1);
#pragma unroll
        for (int ks=0; ks<2; ks++){
            bf16x8 pa = *(const bf16x8*)&PW[w][c16*64 + (((ks*4+g) ^ (c16&7))<<3)];
#pragma unroll
            for (int dt=0; dt<4; dt++){
                int vr = dt*16 + c16;
                bf16x8 vb = *(const bf16x8*)&VTs[buf][vr*64 + (((ks*4+g) ^ (vr&7))<<3)];
                acc[dt] = MFMA_BF16(pa, vb, acc[dt]);
            }
        }
        __builtin_amdgcn_s_setprio(0);

        asm volatile("s_waitcnt vmcnt(0)" ::: "memory");
        __syncthreads();
        buf ^= 1;
    }
#undef STAGE

    // --- epilogue ---
#pragma unroll
    for (int dt=0; dt<4; dt++)
#pragma unroll
        for (int r=0; r<4; r++){
            int qr = qrow + g*4 + r;
            O[(size_t)(b*T_SEQ + qr)*DM + h*HD_ + dt*16 + c16] = acc[dt][r] / lsum[r];
        }
}

// ---------------- launcher ----------------
extern "C" void kernel_launch(void* const* d_in, const int* in_sizes, int n_in,
                              void* d_out, int out_size, void* d_ws, size_t ws_size,
                              hipStream_t stream)
{
    const float* q  = (const float*)d_in[0];
    const float* k  = (const float*)d_in[1];
    const float* v  = (const float*)d_in[2];
    const float* fr = (const float*)d_in[3];
    const float* Wq = (const float*)d_in[4];
    const float* bq = (const float*)d_in[5];
    const float* Wk = (const float*)d_in[6];
    const float* bk = (const float*)d_in[7];
    const float* Wv = (const float*)d_in[8];
    const float* bv = (const float*)d_in[9];
    const float* Wo = (const float*)d_in[10];
    const float* bo = (const float*)d_in[11];
    const float* ap = (const float*)d_in[12];
    const float* an = (const float*)d_in[13];

    const size_t MT = (size_t)(2*T_SEQ) * DM;              // 4M elements
    ushort_t* QKVp = (ushort_t*)d_ws;                      // Q,K,V bf16 (24 MB)
    ushort_t* Vtp  = QKVp + 3*MT;                          // V^T bf16 (8 MB)
    float*    O    = (float*)((char*)d_ws + 4*MT*sizeof(ushort_t)); // 16 MB f32

    dim3 gq(64, 4, 3);
    gemm_qkv_kernel<<<gq, 256, 0, stream>>>(q,k,v,Wq,bq,Wk,bk,Wv,bv,QKVp);

    vtrans_kernel<<<1024, 256, 0, stream>>>(QKVp + 2*MT, Vtp);

    flash_kernel<<<1024, 256, 0, stream>>>(QKVp, QKVp + MT, Vtp, fr, ap, an, O);

    dim3 go(64, 4, 1);
    gemm_out_kernel<<<go, 256, 0, stream>>>(O, Wo, bo, (float*)d_out);
}

// Round 3
// 190.086 us; speedup vs baseline: 1.6063x; 1.4013x over previous
//
#include <hip/hip_runtime.h>

typedef __attribute__((ext_vector_type(8))) __bf16 bf16x8;
typedef __attribute__((ext_vector_type(8))) unsigned short ushort8;
typedef __attribute__((ext_vector_type(4))) float f32x4;
typedef unsigned short ushort_t;

#define MFMA_BF16(A,B,C) __builtin_amdgcn_mfma_f32_16x16x32_bf16(A,B,C,0,0,0)

#define T_SEQ 4096
#define DM 512
#define HD_ 64
#define NH_ 8

#define LOG2E 1.4426950408889634f
#define QSCALE (0.125f * LOG2E)

__device__ __forceinline__ unsigned short f2b(float f){
    unsigned int u = __builtin_bit_cast(unsigned int, f);
    u += 0x7FFFu + ((u >> 16) & 1u);   // round-to-nearest-even
    return (unsigned short)(u >> 16);
}

__device__ __forceinline__ float exp2_fast(float x){
#if __has_builtin(__builtin_amdgcn_exp2f)
    return __builtin_amdgcn_exp2f(x);
#else
    float r; asm("v_exp_f32 %0, %1" : "=v"(r) : "v"(x)); return r;
#endif
}

__device__ __forceinline__ unsigned cvt_pk_bf16(float a, float b){
    unsigned r;
    asm("v_cvt_pk_bf16_f32 %0, %1, %2" : "=v"(r) : "v"(a), "v"(b));
    return r;
}

__device__ __forceinline__ void gload_lds16(const void* g, void* l){
    __builtin_amdgcn_global_load_lds((const __attribute__((address_space(1))) void*)g,
                                     (__attribute__((address_space(3))) void*)l, 16, 0, 0);
}

// ---------------- GEMM: C[M,512] = (A[M,512] @ W[512,512]^T + bias) * scale ----------------
template<int OUT_BF16>
__device__ __forceinline__ void gemm_body(const float* __restrict__ A, const float* __restrict__ W,
                                          const float* __restrict__ bias, void* __restrict__ Cout,
                                          int m0, int n0, float scale)
{
    constexpr int K = 512, N = 512;
    __shared__ ushort_t As[128*64];
    __shared__ ushort_t Bs[128*64];

    const int tid  = threadIdx.x;
    const int lane = tid & 63;
    const int w    = tid >> 6;
    const int g    = lane >> 4;
    const int c16  = lane & 15;
    const int wm   = w >> 1, wn = w & 1;

    f32x4 acc[4][4];
#pragma unroll
    for (int i=0;i<4;i++)
#pragma unroll
        for (int j=0;j<4;j++) acc[i][j] = (f32x4){0.f,0.f,0.f,0.f};

#pragma unroll 1
    for (int kt=0; kt<K/64; kt++){
        __syncthreads();
#pragma unroll
        for (int j=0;j<4;j++){
            int cid = j*256 + tid;
            int row = cid >> 3, ch = cid & 7;
            const float* srcA = A + (size_t)(m0+row)*K + kt*64 + ch*8;
            const float* srcB = W + (size_t)(n0+row)*K + kt*64 + ch*8;
            float4 a0 = *(const float4*)srcA;
            float4 a1 = *(const float4*)(srcA+4);
            float4 b0 = *(const float4*)srcB;
            float4 b1 = *(const float4*)(srcB+4);
            ushort8 va, vb;
            va[0]=f2b(a0.x); va[1]=f2b(a0.y); va[2]=f2b(a0.z); va[3]=f2b(a0.w);
            va[4]=f2b(a1.x); va[5]=f2b(a1.y); va[6]=f2b(a1.z); va[7]=f2b(a1.w);
            vb[0]=f2b(b0.x); vb[1]=f2b(b0.y); vb[2]=f2b(b0.z); vb[3]=f2b(b0.w);
            vb[4]=f2b(b1.x); vb[5]=f2b(b1.y); vb[6]=f2b(b1.z); vb[7]=f2b(b1.w);
            int dst = row*64 + ((ch ^ (row & 7))<<3);
            *(ushort8*)&As[dst] = va;
            *(ushort8*)&Bs[dst] = vb;
        }
        __syncthreads();
#pragma unroll
        for (int ks=0; ks<2; ks++){
            bf16x8 af[4], bfr[4];
#pragma unroll
            for (int f=0; f<4; f++){
                int rowa = wm*64 + f*16 + c16;
                af[f]  = *(const bf16x8*)&As[rowa*64 + (((ks*4+g) ^ (rowa&7))<<3)];
                int rowb = wn*64 + f*16 + c16;
                bfr[f] = *(const bf16x8*)&Bs[rowb*64 + (((ks*4+g) ^ (rowb&7))<<3)];
            }
#pragma unroll
            for (int fm=0; fm<4; fm++)
#pragma unroll
                for (int fn=0; fn<4; fn++)
                    acc[fm][fn] = MFMA_BF16(af[fm], bfr[fn], acc[fm][fn]);
        }
    }
#pragma unroll
    for (int fm=0; fm<4; fm++)
#pragma unroll
        for (int fn=0; fn<4; fn++){
            int col = n0 + wn*64 + fn*16 + c16;
            float bv = bias[col];
#pragma unroll
            for (int r=0; r<4; r++){
                int rowm = m0 + wm*64 + fm*16 + g*4 + r;
                float vv = (acc[fm][fn][r] + bv) * scale;
                if (OUT_BF16) ((ushort_t*)Cout)[(size_t)rowm*N + col] = f2b(vv);
                else          ((float*)Cout)[(size_t)rowm*N + col]   = vv;
            }
        }
}

__global__ __launch_bounds__(256,2) void gemm_qkv_kernel(
    const float* __restrict__ q, const float* __restrict__ k, const float* __restrict__ v,
    const float* __restrict__ Wq, const float* __restrict__ bq,
    const float* __restrict__ Wk, const float* __restrict__ bk,
    const float* __restrict__ Wv, const float* __restrict__ bv,
    ushort_t* __restrict__ QKVp)
{
    int z = blockIdx.z;
    const float* A  = (z==0) ? q  : (z==1 ? k  : v);
    const float* W  = (z==0) ? Wq : (z==1 ? Wk : Wv);
    const float* bb = (z==0) ? bq : (z==1 ? bk : bv);
    float scale = (z==0) ? QSCALE : 1.0f;   // bake 0.125*log2e into Q
    ushort_t* C = QKVp + (size_t)z * (size_t)(2*T_SEQ) * DM;
    gemm_body<1>(A, W, bb, C, blockIdx.x*128, blockIdx.y*128, scale);
}

__global__ __launch_bounds__(256,2) void gemm_out_kernel(
    const float* __restrict__ O, const float* __restrict__ Wo,
    const float* __restrict__ bo, float* __restrict__ out)
{
    gemm_body<0>(O, Wo, bo, out, blockIdx.x*128, blockIdx.y*128, 1.0f);
}

// ---------------- V transpose: Vt[bh][d][t] <- V[b*T+t][h*64+d] ----------------
__global__ __launch_bounds__(256) void vtrans_kernel(const ushort_t* __restrict__ Vp,
                                                     ushort_t* __restrict__ Vt)
{
    int blk = blockIdx.x;            // 16 bh * 64 t-tiles = 1024
    int bh  = blk >> 6;
    int t0  = (blk & 63) << 6;
    int b = bh >> 3, h = bh & 7;
    __shared__ ushort_t tile[64][65];
    const int tid = threadIdx.x;
    const ushort_t* src = Vp + (size_t)(b*T_SEQ + t0)*DM + h*HD_;
#pragma unroll
    for (int p=0; p<2; p++){
        int row = (tid>>3) + p*32;
        int c8  = (tid&7)*8;
        ushort8 v = *(const ushort8*)(src + (size_t)row*DM + c8);
#pragma unroll
        for (int j=0;j<8;j++) tile[row][c8+j] = v[j];
    }
    __syncthreads();
    ushort_t* dst = Vt + (size_t)bh*HD_*T_SEQ + t0;
#pragma unroll
    for (int p=0; p<2; p++){
        int d  = (tid>>3) + p*32;
        int c8 = (tid&7)*8;
        ushort8 v;
#pragma unroll
        for (int j=0;j<8;j++) v[j] = tile[c8+j][d];
        *(ushort8*)(dst + (size_t)d*T_SEQ + c8) = v;
    }
}

// ---------------- Flash attention (swapped-operand, log2 domain) ----------------
// 256 thr (4 waves), 64 q rows/block (wave = 16 rows), KV tile 64, dbuf K/V^T.
// Swapped QK^T: S^T = mfma(K, Q) -> each lane owns ONE q-row (col=c16), 16 kv values.
__global__ __launch_bounds__(256,4) void flash_kernel(
    const ushort_t* __restrict__ Qp, const ushort_t* __restrict__ Kp, const ushort_t* __restrict__ Vt,
    const float* __restrict__ frac, const float* __restrict__ alphap, const float* __restrict__ alphan,
    float* __restrict__ O)
{
    // XCD-aware: 2 bh per XCD; their K/V (2 MB) live in that XCD's L2
    int i    = blockIdx.x;
    int slot = i & 7;
    int seq  = i >> 3;
    int bh   = slot*2 + (seq >> 6);
    int qt   = seq & 63;
    int b    = bh >> 3, h = bh & 7;
    int q0   = qt * 64;

    const int tid  = threadIdx.x;
    const int w    = tid >> 6;
    const int lane = tid & 63;
    const int g    = lane >> 4;
    const int c16  = lane & 15;

    __shared__ ushort_t Ks [2][64*64];   // [kv][d], chunk ^ (row&7)
    __shared__ ushort_t VTs[2][64*64];   // [d][kv], chunk ^ (row&7)
    __shared__ ushort_t PW [4][16*64];   // per-wave P^T as [q][kv], pair-swizzled

    const ushort_t* Qbase = Qp + (size_t)(b*T_SEQ)*DM + h*HD_;
    const ushort_t* Kbase = Kp + (size_t)(b*T_SEQ)*DM + h*HD_;
    const ushort_t* Vtb   = Vt + (size_t)bh*HD_*T_SEQ;
    const float*    fr    = frac + b*T_SEQ;
    const float apl = alphap[h] * LOG2E, anl = alphan[h] * LOG2E;
    const int qrow = q0 + w*16;

    // Q fragments (B-operand: col = c16, k = ks*32 + g*8 + e)
    bf16x8 qa[2];
#pragma unroll
    for (int ks=0; ks<2; ks++)
        qa[ks] = *(const bf16x8*)(Qbase + (size_t)(qrow + c16)*DM + ks*32 + g*8);
    const float fi = fr[qrow + c16];     // this lane's q-row frac

    float m2   = -1e30f;                 // running max (log2 domain)
    float lsum = 0.f;
    f32x4 acc[4];                        // O^T: lane holds q=c16, d = dt*16+g*4+r
#pragma unroll
    for (int dt=0; dt<4; dt++) acc[dt] = (f32x4){0.f,0.f,0.f,0.f};

#define STAGE(BUF, KV0)                                                          \
    {                                                                            \
        _Pragma("unroll")                                                        \
        for (int j=0;j<2;j++){                                                   \
            int cb  = (j*4 + w)*64;                                              \
            int idx = cb + lane;                                                 \
            int row = idx >> 3, cc = idx & 7;                                    \
            int cs  = cc ^ (row & 7);                                            \
            gload_lds16(Kbase + (size_t)((KV0)+row)*DM + cs*8, &Ks[BUF][cb*8]);  \
            gload_lds16(Vtb + (size_t)row*T_SEQ + (KV0) + cs*8, &VTs[BUF][cb*8]);\
        }                                                                        \
    }

    STAGE(0, 0);
    asm volatile("s_waitcnt vmcnt(0)" ::: "memory");
    __syncthreads();

    int buf = 0;
#pragma unroll 1
    for (int kt=0; kt<T_SEQ/64; kt++){
        int kv0 = kt*64;
        if (kt+1 < T_SEQ/64) STAGE(buf^1, kv0+64);

        // --- S^T = K Q^T (pre-scaled by 0.125*log2e via Q) ---
        f32x4 s[4];                      // s[n][r]: kv = n*16+g*4+r, q = c16
#pragma unroll
        for (int n=0; n<4; n++) s[n] = (f32x4){0.f,0.f,0.f,0.f};
        __builtin_amdgcn_s_setprio(1);
#pragma unroll
        for (int n=0; n<4; n++){
#pragma unroll
            for (int ks=0; ks<2; ks++){
                int row = n*16 + c16;
                bf16x8 kb = *(const bf16x8*)&Ks[buf][row*64 + (((ks*4+g) ^ (row&7))<<3)];
                s[n] = MFMA_BF16(kb, qa[ks], s[n]);   // A=K, B=Q
            }
        }
        __builtin_amdgcn_s_setprio(0);

        // --- bias (log2 domain) ---
        float mx;
#pragma unroll
        for (int n=0; n<4; n++){
            f32x4 fj = *(const f32x4*)&fr[kv0 + n*16 + g*4];
#pragma unroll
            for (int r=0; r<4; r++){
                float dd = fj[r] - fi;
                float co = (dd > 0.f) ? apl : anl;
                s[n][r] = fmaf(co, dd, s[n][r]);
            }
            float t = fmaxf(fmaxf(s[n][0], s[n][1]), fmaxf(s[n][2], s[n][3]));
            mx = (n==0) ? t : fmaxf(mx, t);
        }
        // cross-lane row max (lanes c16, c16+16, c16+32, c16+48 share q-row)
        mx = fmaxf(mx, __shfl_xor(mx, 16));
        mx = fmaxf(mx, __shfl_xor(mx, 32));

        // --- defer-max rescale (threshold 12 in log2 ~ e^8.3) ---
        if (__any(mx > m2 + 12.0f)){
            float mnew = fmaxf(m2, mx);
            float fac  = exp2_fast(m2 - mnew);
            lsum *= fac;
#pragma unroll
            for (int dt=0; dt<4; dt++)
#pragma unroll
                for (int r=0; r<4; r++) acc[dt][r] *= fac;
            m2 = mnew;
        }

        // --- exp2, row-sum, pack P -> LDS ---
        float tn[4];
#pragma unroll
        for (int n=0; n<4; n++){
#pragma unroll
            for (int r=0; r<4; r++) s[n][r] = exp2_fast(s[n][r] - m2);
            tn[n] = (s[n][0] + s[n][1]) + (s[n][2] + s[n][3]);
            unsigned pk0 = cvt_pk_bf16(s[n][0], s[n][1]);
            unsigned pk1 = cvt_pk_bf16(s[n][2], s[n][3]);
            uint2 u; u.x = pk0; u.y = pk1;
            int off = c16*64 + (((n*2 + (g>>1)) ^ (c16 & 7))<<3) + ((g&1)<<2);
            *(uint2*)&PW[w][off] = u;
        }
        float rs = (tn[0] + tn[1]) + (tn[2] + tn[3]);
        rs += __shfl_xor(rs, 16);
        rs += __shfl_xor(rs, 32);
        lsum += rs;

        // --- PV: O^T += V^T P^T ---
        __builtin_amdgcn_s_setprio(1);
#pragma unroll
        for (int ks=0; ks<2; ks++){
            bf16x8 pb = *(const bf16x8*)&PW[w][c16*64 + (((ks*4+g) ^ (c16&7))<<3)];
#pragma unroll
            for (int dt=0; dt<4; dt++){
                int vr = dt*16 + c16;
                bf16x8 vb = *(const bf16x8*)&VTs[buf][vr*64 + (((ks*4+g) ^ (vr&7))<<3)];
                acc[dt] = MFMA_BF16(vb, pb, acc[dt]);  // A=V^T, B=P^T
            }
        }
        __builtin_amdgcn_s_setprio(0);

        asm volatile("s_waitcnt vmcnt(0)" ::: "memory");
        __syncthreads();
        buf ^= 1;
    }
#undef STAGE

    // --- epilogue: O[b, qrow+c16, h*64 + dt*16 + g*4 + r] ---
    float inv = 1.0f / lsum;
    float* orow = O + (size_t)(b*T_SEQ + qrow + c16)*DM + h*HD_;
#pragma unroll
    for (int dt=0; dt<4; dt++){
        float4 o4;
        o4.x = acc[dt][0]*inv; o4.y = acc[dt][1]*inv;
        o4.z = acc[dt][2]*inv; o4.w = acc[dt][3]*inv;
        *(float4*)(orow + dt*16 + g*4) = o4;
    }
}

// ---------------- launcher ----------------
extern "C" void kernel_launch(void* const* d_in, const int* in_sizes, int n_in,
                              void* d_out, int out_size, void* d_ws, size_t ws_size,
                              hipStream_t stream)
{
    const float* q  = (const float*)d_in[0];
    const float* k  = (const float*)d_in[1];
    const float* v  = (const float*)d_in[2];
    const float* fr = (const float*)d_in[3];
    const float* Wq = (const float*)d_in[4];
    const float* bq = (const float*)d_in[5];
    const float* Wk = (const float*)d_in[6];
    const float* bk = (const float*)d_in[7];
    const float* Wv = (const float*)d_in[8];
    const float* bv = (const float*)d_in[9];
    const float* Wo = (const float*)d_in[10];
    const float* bo = (const float*)d_in[11];
    const float* ap = (const float*)d_in[12];
    const float* an = (const float*)d_in[13];

    const size_t MT = (size_t)(2*T_SEQ) * DM;              // 4M elements
    ushort_t* QKVp = (ushort_t*)d_ws;                      // Q,K,V bf16 (24 MB)
    ushort_t* Vtp  = QKVp + 3*MT;                          // V^T bf16 (8 MB)
    float*    O    = (float*)((char*)d_ws + 4*MT*sizeof(ushort_t)); // 16 MB f32

    dim3 gq(64, 4, 3);
    gemm_qkv_kernel<<<gq, 256, 0, stream>>>(q,k,v,Wq,bq,Wk,bk,Wv,bv,QKVp);

    vtrans_kernel<<<1024, 256, 0, stream>>>(QKVp + 2*MT, Vtp);

    flash_kernel<<<1024, 256, 0, stream>>>(QKVp, QKVp + MT, Vtp, fr, ap, an, O);

    dim3 go(64, 4, 1);
    gemm_out_kernel<<<go, 256, 0, stream>>>(O, Wo, bo, (float*)d_out);
}

// Round 7
// 177.099 us; speedup vs baseline: 1.7241x; 1.0733x over previous
//
#include <hip/hip_runtime.h>

typedef __attribute__((ext_vector_type(8))) __bf16 bf16x8;
typedef __attribute__((ext_vector_type(8))) unsigned short ushort8;
typedef __attribute__((ext_vector_type(4))) float f32x4;
typedef unsigned short ushort_t;

#define MFMA_BF16(A,B,C) __builtin_amdgcn_mfma_f32_16x16x32_bf16(A,B,C,0,0,0)

#define T_SEQ 4096
#define DM 512
#define HD_ 64
#define NH_ 8

#define LOG2E 1.4426950408889634f
#define QSCALE (0.125f * LOG2E)

__device__ __forceinline__ unsigned short f2b(float f){
    unsigned int u = __builtin_bit_cast(unsigned int, f);
    u += 0x7FFFu + ((u >> 16) & 1u);   // round-to-nearest-even
    return (unsigned short)(u >> 16);
}

__device__ __forceinline__ float exp2_fast(float x){
#if __has_builtin(__builtin_amdgcn_exp2f)
    return __builtin_amdgcn_exp2f(x);
#else
    float r; asm("v_exp_f32 %0, %1" : "=v"(r) : "v"(x)); return r;
#endif
}

__device__ __forceinline__ unsigned cvt_pk_bf16(float a, float b){
    unsigned r;
    asm("v_cvt_pk_bf16_f32 %0, %1, %2" : "=v"(r) : "v"(a), "v"(b));
    return r;
}

__device__ __forceinline__ void gload_lds16(const void* g, void* l){
    __builtin_amdgcn_global_load_lds((const __attribute__((address_space(1))) void*)g,
                                     (__attribute__((address_space(3))) void*)l, 16, 0, 0);
}

// ---------------- GEMM: C[M,512] = (A[M,512] @ W[512,512]^T + bias) * scale ----------------
template<int OUT_BF16>
__device__ __forceinline__ void gemm_body(const float* __restrict__ A, const float* __restrict__ W,
                                          const float* __restrict__ bias, void* __restrict__ Cout,
                                          int m0, int n0, float scale)
{
    constexpr int K = 512, N = 512;
    __shared__ ushort_t As[128*64];
    __shared__ ushort_t Bs[128*64];

    const int tid  = threadIdx.x;
    const int lane = tid & 63;
    const int w    = tid >> 6;
    const int g    = lane >> 4;
    const int c16  = lane & 15;
    const int wm   = w >> 1, wn = w & 1;

    f32x4 acc[4][4];
#pragma unroll
    for (int i=0;i<4;i++)
#pragma unroll
        for (int j=0;j<4;j++) acc[i][j] = (f32x4){0.f,0.f,0.f,0.f};

#pragma unroll 1
    for (int kt=0; kt<K/64; kt++){
        __syncthreads();
#pragma unroll
        for (int j=0;j<4;j++){
            int cid = j*256 + tid;
            int row = cid >> 3, ch = cid & 7;
            const float* srcA = A + (size_t)(m0+row)*K + kt*64 + ch*8;
            const float* srcB = W + (size_t)(n0+row)*K + kt*64 + ch*8;
            float4 a0 = *(const float4*)srcA;
            float4 a1 = *(const float4*)(srcA+4);
            float4 b0 = *(const float4*)srcB;
            float4 b1 = *(const float4*)(srcB+4);
            ushort8 va, vb;
            va[0]=f2b(a0.x); va[1]=f2b(a0.y); va[2]=f2b(a0.z); va[3]=f2b(a0.w);
            va[4]=f2b(a1.x); va[5]=f2b(a1.y); va[6]=f2b(a1.z); va[7]=f2b(a1.w);
            vb[0]=f2b(b0.x); vb[1]=f2b(b0.y); vb[2]=f2b(b0.z); vb[3]=f2b(b0.w);
            vb[4]=f2b(b1.x); vb[5]=f2b(b1.y); vb[6]=f2b(b1.z); vb[7]=f2b(b1.w);
            int dst = row*64 + ((ch ^ (row & 7))<<3);
            *(ushort8*)&As[dst] = va;
            *(ushort8*)&Bs[dst] = vb;
        }
        __syncthreads();
#pragma unroll
        for (int ks=0; ks<2; ks++){
            bf16x8 af[4], bfr[4];
#pragma unroll
            for (int f=0; f<4; f++){
                int rowa = wm*64 + f*16 + c16;
                af[f]  = *(const bf16x8*)&As[rowa*64 + (((ks*4+g) ^ (rowa&7))<<3)];
                int rowb = wn*64 + f*16 + c16;
                bfr[f] = *(const bf16x8*)&Bs[rowb*64 + (((ks*4+g) ^ (rowb&7))<<3)];
            }
#pragma unroll
            for (int fm=0; fm<4; fm++)
#pragma unroll
                for (int fn=0; fn<4; fn++)
                    acc[fm][fn] = MFMA_BF16(af[fm], bfr[fn], acc[fm][fn]);
        }
    }
#pragma unroll
    for (int fm=0; fm<4; fm++)
#pragma unroll
        for (int fn=0; fn<4; fn++){
            int col = n0 + wn*64 + fn*16 + c16;
            float bv = bias[col];
#pragma unroll
            for (int r=0; r<4; r++){
                int rowm = m0 + wm*64 + fm*16 + g*4 + r;
                float vv = (acc[fm][fn][r] + bv) * scale;
                if (OUT_BF16) ((ushort_t*)Cout)[(size_t)rowm*N + col] = f2b(vv);
                else          ((float*)Cout)[(size_t)rowm*N + col]   = vv;
            }
        }
}

__global__ __launch_bounds__(256,2) void gemm_qkv_kernel(
    const float* __restrict__ q, const float* __restrict__ k, const float* __restrict__ v,
    const float* __restrict__ Wq, const float* __restrict__ bq,
    const float* __restrict__ Wk, const float* __restrict__ bk,
    const float* __restrict__ Wv, const float* __restrict__ bv,
    ushort_t* __restrict__ QKVp)
{
    int z = blockIdx.z;
    const float* A  = (z==0) ? q  : (z==1 ? k  : v);
    const float* W  = (z==0) ? Wq : (z==1 ? Wk : Wv);
    const float* bb = (z==0) ? bq : (z==1 ? bk : bv);
    float scale = (z==0) ? QSCALE : 1.0f;   // bake 0.125*log2e into Q
    ushort_t* C = QKVp + (size_t)z * (size_t)(2*T_SEQ) * DM;
    gemm_body<1>(A, W, bb, C, blockIdx.x*128, blockIdx.y*128, scale);
}

__global__ __launch_bounds__(256,2) void gemm_out_kernel(
    const float* __restrict__ O, const float* __restrict__ Wo,
    const float* __restrict__ bo, float* __restrict__ out)
{
    gemm_body<0>(O, Wo, bo, out, blockIdx.x*128, blockIdx.y*128, 1.0f);
}

// ---------------- V transpose: Vt[bh][d][t] <- V[b*T+t][h*64+d] ----------------
__global__ __launch_bounds__(256) void vtrans_kernel(const ushort_t* __restrict__ Vp,
                                                     ushort_t* __restrict__ Vt)
{
    int blk = blockIdx.x;            // 16 bh * 64 t-tiles = 1024
    int bh  = blk >> 6;
    int t0  = (blk & 63) << 6;
    int b = bh >> 3, h = bh & 7;
    __shared__ ushort_t tile[64][65];
    const int tid = threadIdx.x;
    const ushort_t* src = Vp + (size_t)(b*T_SEQ + t0)*DM + h*HD_;
#pragma unroll
    for (int p=0; p<2; p++){
        int row = (tid>>3) + p*32;
        int c8  = (tid&7)*8;
        ushort8 v = *(const ushort8*)(src + (size_t)row*DM + c8);
#pragma unroll
        for (int j=0;j<8;j++) tile[row][c8+j] = v[j];
    }
    __syncthreads();
    ushort_t* dst = Vt + (size_t)bh*HD_*T_SEQ + t0;
#pragma unroll
    for (int p=0; p<2; p++){
        int d  = (tid>>3) + p*32;
        int c8 = (tid&7)*8;
        ushort8 v;
#pragma unroll
        for (int j=0;j<8;j++) v[j] = tile[c8+j][d];
        *(ushort8*)(dst + (size_t)d*T_SEQ + c8) = v;
    }
}

// ---------------- Flash attention (r3 numerics, 8 waves, QBLK=128) ----------------
// 512 thr (8 waves), 128 q rows/block (wave = 16 rows), KV tile 64, dbuf K/V^T.
// Swapped QK^T: S^T = mfma(K, Q): lane owns q-row c16, kv = n*16+g*4+r.
// Online softmax with defer-max (r3-proven). LDS = 48 KiB -> 3 blocks/CU capacity;
// grid 512 fully co-resident (no tail).
__global__ __launch_bounds__(512,4) void flash_kernel(
    const ushort_t* __restrict__ Qp, const ushort_t* __restrict__ Kp, const ushort_t* __restrict__ Vt,
    const float* __restrict__ frac, const float* __restrict__ alphap, const float* __restrict__ alphan,
    float* __restrict__ O)
{
    // XCD-aware: 2 bh per XCD slot; their K/V (2 MB) live in that XCD's L2
    int i    = blockIdx.x;
    int slot = i & 7;
    int seq  = i >> 3;                   // [0,64)
    int bh   = slot*2 + (seq >> 5);
    int qt   = seq & 31;
    int b    = bh >> 3, h = bh & 7;
    int q0   = qt * 128;

    const int tid  = threadIdx.x;
    const int w    = tid >> 6;           // [0,8)
    const int lane = tid & 63;
    const int g    = lane >> 4;
    const int c16  = lane & 15;

    __shared__ ushort_t Ks [2][64*64];   // [kv][d], chunk ^ (row&7)
    __shared__ ushort_t VTs[2][64*64];   // [d][kv], chunk ^ (row&7)
    __shared__ ushort_t PW [8][16*64];   // per-wave P^T as [q][kv], pair-swizzled

    const ushort_t* Qbase = Qp + (size_t)(b*T_SEQ)*DM + h*HD_;
    const ushort_t* Kbase = Kp + (size_t)(b*T_SEQ)*DM + h*HD_;
    const ushort_t* Vtb   = Vt + (size_t)bh*HD_*T_SEQ;
    const float*    fr    = frac + b*T_SEQ;
    const float c1 = 0.5f*(alphap[h] + alphan[h]) * LOG2E;   // bias = c1*dd + c2*|dd|
    const float c2 = 0.5f*(alphap[h] - alphan[h]) * LOG2E;   // == ap*max(dd,0)+an*min(dd,0)
    const int qrow = q0 + w*16;

    // Q fragments (B-operand: col = c16, k = ks*32 + g*8 + e)
    bf16x8 qa[2];
#pragma unroll
    for (int ks=0; ks<2; ks++)
        qa[ks] = *(const bf16x8*)(Qbase + (size_t)(qrow + c16)*DM + ks*32 + g*8);
    const float fi = fr[qrow + c16];     // this lane's q-row frac

    float m2   = -1e30f;                 // running max (log2 domain)
    float lsum = 0.f;
    f32x4 acc[4];                        // O^T: lane holds q=c16, d = dt*16+g*4+r
#pragma unroll
    for (int dt=0; dt<4; dt++) acc[dt] = (f32x4){0.f,0.f,0.f,0.f};

#define STAGE(BUF, KV0)                                                          \
    {                                                                            \
        int cb  = w*64;                                                          \
        int idx = cb + lane;                                                     \
        int row = idx >> 3, cc = idx & 7;                                        \
        int cs  = cc ^ (row & 7);                                                \
        gload_lds16(Kbase + (size_t)((KV0)+row)*DM + cs*8, &Ks[BUF][cb*8]);      \
        gload_lds16(Vtb + (size_t)row*T_SEQ + (KV0) + cs*8, &VTs[BUF][cb*8]);    \
    }

    STAGE(0, 0);
    asm volatile("s_waitcnt vmcnt(0)" ::: "memory");
    __syncthreads();

    int buf = 0;
#pragma unroll 1
    for (int kt=0; kt<T_SEQ/64; kt++){
        int kv0 = kt*64;
        if (kt+1 < T_SEQ/64) STAGE(buf^1, kv0+64);

        // --- S^T = K Q^T (Q pre-scaled by 0.125*log2e) ---
        f32x4 s[4];                      // s[n][r]: kv = n*16+g*4+r, q = c16
#pragma unroll
        for (int n=0; n<4; n++) s[n] = (f32x4){0.f,0.f,0.f,0.f};
        __builtin_amdgcn_s_setprio(1);
#pragma unroll
        for (int n=0; n<4; n++){
#pragma unroll
            for (int ks=0; ks<2; ks++){
                int row = n*16 + c16;
                bf16x8 kb = *(const bf16x8*)&Ks[buf][row*64 + (((ks*4+g) ^ (row&7))<<3)];
                s[n] = MFMA_BF16(kb, qa[ks], s[n]);   // A=K, B=Q
            }
        }
        __builtin_amdgcn_s_setprio(0);

        // --- bias (log2 domain, select-free algebra) ---
        float mx;
#pragma unroll
        for (int n=0; n<4; n++){
            f32x4 fj = *(const f32x4*)&fr[kv0 + n*16 + g*4];
#pragma unroll
            for (int r=0; r<4; r++){
                float dd = fj[r] - fi;
                s[n][r] = fmaf(c1, dd, fmaf(c2, fabsf(dd), s[n][r]));
            }
            float t = fmaxf(fmaxf(s[n][0], s[n][1]), fmaxf(s[n][2], s[n][3]));
            mx = (n==0) ? t : fmaxf(mx, t);
        }
        // cross-lane row max (lanes c16, c16+16, c16+32, c16+48 share q-row)
        mx = fmaxf(mx, __shfl_xor(mx, 16));
        mx = fmaxf(mx, __shfl_xor(mx, 32));

        // --- defer-max rescale (threshold 12 in log2 ~ e^8.3) ---
        if (__any(mx > m2 + 12.0f)){
            float mnew = fmaxf(m2, mx);
            float fac  = exp2_fast(m2 - mnew);
            lsum *= fac;
#pragma unroll
            for (int dt=0; dt<4; dt++)
#pragma unroll
                for (int r=0; r<4; r++) acc[dt][r] *= fac;
            m2 = mnew;
        }

        // --- exp2, row-sum, pack P -> LDS ---
        float tn[4];
#pragma unroll
        for (int n=0; n<4; n++){
#pragma unroll
            for (int r=0; r<4; r++) s[n][r] = exp2_fast(s[n][r] - m2);
            tn[n] = (s[n][0] + s[n][1]) + (s[n][2] + s[n][3]);
            unsigned pk0 = cvt_pk_bf16(s[n][0], s[n][1]);
            unsigned pk1 = cvt_pk_bf16(s[n][2], s[n][3]);
            uint2 u; u.x = pk0; u.y = pk1;
            int off = c16*64 + (((n*2 + (g>>1)) ^ (c16 & 7))<<3) + ((g&1)<<2);
            *(uint2*)&PW[w][off] = u;
        }
        float rs = (tn[0] + tn[1]) + (tn[2] + tn[3]);
        rs += __shfl_xor(rs, 16);
        rs += __shfl_xor(rs, 32);
        lsum += rs;

        // --- fence: order PW ds_writes before pb ds_reads (TBAA-blind pair) ---
        asm volatile("s_waitcnt lgkmcnt(0)" ::: "memory");
        __builtin_amdgcn_sched_barrier(0);

        // --- PV: O^T += V^T P^T ---
        __builtin_amdgcn_s_setprio(1);
#pragma unroll
        for (int ks=0; ks<2; ks++){
            bf16x8 pb = *(const bf16x8*)&PW[w][c16*64 + (((ks*4+g) ^ (c16&7))<<3)];
#pragma unroll
            for (int dt=0; dt<4; dt++){
                int vr = dt*16 + c16;
                bf16x8 vb = *(const bf16x8*)&VTs[buf][vr*64 + (((ks*4+g) ^ (vr&7))<<3)];
                acc[dt] = MFMA_BF16(vb, pb, acc[dt]);  // A=V^T, B=P^T
            }
        }
        __builtin_amdgcn_s_setprio(0);

        asm volatile("s_waitcnt vmcnt(0)" ::: "memory");
        __syncthreads();
        buf ^= 1;
    }
#undef STAGE

    // --- epilogue: O[b, qrow+c16, h*64 + dt*16 + g*4 + r] ---
    float inv = 1.0f / lsum;
    float* orow = O + (size_t)(b*T_SEQ + qrow + c16)*DM + h*HD_;
#pragma unroll
    for (int dt=0; dt<4; dt++){
        float4 o4;
        o4.x = acc[dt][0]*inv; o4.y = acc[dt][1]*inv;
        o4.z = acc[dt][2]*inv; o4.w = acc[dt][3]*inv;
        *(float4*)(orow + dt*16 + g*4) = o4;
    }
}

// ---------------- launcher ----------------
extern "C" void kernel_launch(void* const* d_in, const int* in_sizes, int n_in,
                              void* d_out, int out_size, void* d_ws, size_t ws_size,
                              hipStream_t stream)
{
    const float* q  = (const float*)d_in[0];
    const float* k  = (const float*)d_in[1];
    const float* v  = (const float*)d_in[2];
    const float* fr = (const float*)d_in[3];
    const float* Wq = (const float*)d_in[4];
    const float* bq = (const float*)d_in[5];
    const float* Wk = (const float*)d_in[6];
    const float* bk = (const float*)d_in[7];
    const float* Wv = (const float*)d_in[8];
    const float* bv = (const float*)d_in[9];
    const float* Wo = (const float*)d_in[10];
    const float* bo = (const float*)d_in[11];
    const float* ap = (const float*)d_in[12];
    const float* an = (const float*)d_in[13];

    const size_t MT = (size_t)(2*T_SEQ) * DM;              // 4M elements
    ushort_t* QKVp = (ushort_t*)d_ws;                      // Q,K,V bf16 (24 MB)
    ushort_t* Vtp  = QKVp + 3*MT;                          // V^T bf16 (8 MB)
    float*    O    = (float*)((char*)d_ws + 4*MT*sizeof(ushort_t)); // 16 MB f32

    dim3 gq(64, 4, 3);
    gemm_qkv_kernel<<<gq, 256, 0, stream>>>(q,k,v,Wq,bq,Wk,bk,Wv,bv,QKVp);

    vtrans_kernel<<<1024, 256, 0, stream>>>(QKVp + 2*MT, Vtp);

    flash_kernel<<<512, 512, 0, stream>>>(QKVp, QKVp + MT, Vtp, fr, ap, an, O);

    dim3 go(64, 4, 1);
    gemm_out_kernel<<<go, 256, 0, stream>>>(O, Wo, bo, (float*)d_out);
}

// Round 8
// 171.556 us; speedup vs baseline: 1.7798x; 1.0323x over previous
//
#include <hip/hip_runtime.h>

typedef __attribute__((ext_vector_type(8))) __bf16 bf16x8;
typedef __attribute__((ext_vector_type(8))) unsigned short ushort8;
typedef __attribute__((ext_vector_type(4))) float f32x4;
typedef unsigned short ushort_t;

#define MFMA_BF16(A,B,C) __builtin_amdgcn_mfma_f32_16x16x32_bf16(A,B,C,0,0,0)

#define T_SEQ 4096
#define DM 512
#define HD_ 64
#define NH_ 8

#define LOG2E 1.4426950408889634f
#define QSCALE (0.125f * LOG2E)

__device__ __forceinline__ unsigned short f2b(float f){
    unsigned int u = __builtin_bit_cast(unsigned int, f);
    u += 0x7FFFu + ((u >> 16) & 1u);   // round-to-nearest-even
    return (unsigned short)(u >> 16);
}

__device__ __forceinline__ float exp2_fast(float x){
#if __has_builtin(__builtin_amdgcn_exp2f)
    return __builtin_amdgcn_exp2f(x);
#else
    float r; asm("v_exp_f32 %0, %1" : "=v"(r) : "v"(x)); return r;
#endif
}

__device__ __forceinline__ unsigned cvt_pk_bf16(float a, float b){
    unsigned r;
    asm("v_cvt_pk_bf16_f32 %0, %1, %2" : "=v"(r) : "v"(a), "v"(b));
    return r;
}

__device__ __forceinline__ void gload_lds16(const void* g, void* l){
    __builtin_amdgcn_global_load_lds((const __attribute__((address_space(1))) void*)g,
                                     (__attribute__((address_space(3))) void*)l, 16, 0, 0);
}

// ---------------- GEMM: C[M,512] = (A[M,512] @ W[512,512]^T + bias) * scale ----------------
template<int OUT_BF16>
__device__ __forceinline__ void gemm_body(const float* __restrict__ A, const float* __restrict__ W,
                                          const float* __restrict__ bias, void* __restrict__ Cout,
                                          int m0, int n0, float scale)
{
    constexpr int K = 512, N = 512;
    __shared__ ushort_t As[128*64];
    __shared__ ushort_t Bs[128*64];

    const int tid  = threadIdx.x;
    const int lane = tid & 63;
    const int w    = tid >> 6;
    const int g    = lane >> 4;
    const int c16  = lane & 15;
    const int wm   = w >> 1, wn = w & 1;

    f32x4 acc[4][4];
#pragma unroll
    for (int i=0;i<4;i++)
#pragma unroll
        for (int j=0;j<4;j++) acc[i][j] = (f32x4){0.f,0.f,0.f,0.f};

#pragma unroll 1
    for (int kt=0; kt<K/64; kt++){
        __syncthreads();
#pragma unroll
        for (int j=0;j<4;j++){
            int cid = j*256 + tid;
            int row = cid >> 3, ch = cid & 7;
            const float* srcA = A + (size_t)(m0+row)*K + kt*64 + ch*8;
            const float* srcB = W + (size_t)(n0+row)*K + kt*64 + ch*8;
            float4 a0 = *(const float4*)srcA;
            float4 a1 = *(const float4*)(srcA+4);
            float4 b0 = *(const float4*)srcB;
            float4 b1 = *(const float4*)(srcB+4);
            ushort8 va, vb;
            va[0]=f2b(a0.x); va[1]=f2b(a0.y); va[2]=f2b(a0.z); va[3]=f2b(a0.w);
            va[4]=f2b(a1.x); va[5]=f2b(a1.y); va[6]=f2b(a1.z); va[7]=f2b(a1.w);
            vb[0]=f2b(b0.x); vb[1]=f2b(b0.y); vb[2]=f2b(b0.z); vb[3]=f2b(b0.w);
            vb[4]=f2b(b1.x); vb[5]=f2b(b1.y); vb[6]=f2b(b1.z); vb[7]=f2b(b1.w);
            int dst = row*64 + ((ch ^ (row & 7))<<3);
            *(ushort8*)&As[dst] = va;
            *(ushort8*)&Bs[dst] = vb;
        }
        __syncthreads();
#pragma unroll
        for (int ks=0; ks<2; ks++){
            bf16x8 af[4], bfr[4];
#pragma unroll
            for (int f=0; f<4; f++){
                int rowa = wm*64 + f*16 + c16;
                af[f]  = *(const bf16x8*)&As[rowa*64 + (((ks*4+g) ^ (rowa&7))<<3)];
                int rowb = wn*64 + f*16 + c16;
                bfr[f] = *(const bf16x8*)&Bs[rowb*64 + (((ks*4+g) ^ (rowb&7))<<3)];
            }
#pragma unroll
            for (int fm=0; fm<4; fm++)
#pragma unroll
                for (int fn=0; fn<4; fn++)
                    acc[fm][fn] = MFMA_BF16(af[fm], bfr[fn], acc[fm][fn]);
        }
    }
#pragma unroll
    for (int fm=0; fm<4; fm++)
#pragma unroll
        for (int fn=0; fn<4; fn++){
            int col = n0 + wn*64 + fn*16 + c16;
            float bv = bias[col];
#pragma unroll
            for (int r=0; r<4; r++){
                int rowm = m0 + wm*64 + fm*16 + g*4 + r;
                float vv = (acc[fm][fn][r] + bv) * scale;
                if (OUT_BF16) ((ushort_t*)Cout)[(size_t)rowm*N + col] = f2b(vv);
                else          ((float*)Cout)[(size_t)rowm*N + col]   = vv;
            }
        }
}

__global__ __launch_bounds__(256,2) void gemm_qkv_kernel(
    const float* __restrict__ q, const float* __restrict__ k, const float* __restrict__ v,
    const float* __restrict__ Wq, const float* __restrict__ bq,
    const float* __restrict__ Wk, const float* __restrict__ bk,
    const float* __restrict__ Wv, const float* __restrict__ bv,
    ushort_t* __restrict__ QKVp)
{
    int z = blockIdx.z;
    const float* A  = (z==0) ? q  : (z==1 ? k  : v);
    const float* W  = (z==0) ? Wq : (z==1 ? Wk : Wv);
    const float* bb = (z==0) ? bq : (z==1 ? bk : bv);
    float scale = (z==0) ? QSCALE : 1.0f;   // bake 0.125*log2e into Q
    ushort_t* C = QKVp + (size_t)z * (size_t)(2*T_SEQ) * DM;
    gemm_body<1>(A, W, bb, C, blockIdx.x*128, blockIdx.y*128, scale);
}

__global__ __launch_bounds__(256,2) void gemm_out_kernel(
    const float* __restrict__ O, const float* __restrict__ Wo,
    const float* __restrict__ bo, float* __restrict__ out)
{
    gemm_body<0>(O, Wo, bo, out, blockIdx.x*128, blockIdx.y*128, 1.0f);
}

// ---------------- V transpose: Vt[bh][d][t] <- V[b*T+t][h*64+d] ----------------
__global__ __launch_bounds__(256) void vtrans_kernel(const ushort_t* __restrict__ Vp,
                                                     ushort_t* __restrict__ Vt)
{
    int blk = blockIdx.x;            // 16 bh * 64 t-tiles = 1024
    int bh  = blk >> 6;
    int t0  = (blk & 63) << 6;
    int b = bh >> 3, h = bh & 7;
    __shared__ ushort_t tile[64][65];
    const int tid = threadIdx.x;
    const ushort_t* src = Vp + (size_t)(b*T_SEQ + t0)*DM + h*HD_;
#pragma unroll
    for (int p=0; p<2; p++){
        int row = (tid>>3) + p*32;
        int c8  = (tid&7)*8;
        ushort8 v = *(const ushort8*)(src + (size_t)row*DM + c8);
#pragma unroll
        for (int j=0;j<8;j++) tile[row][c8+j] = v[j];
    }
    __syncthreads();
    ushort_t* dst = Vt + (size_t)bh*HD_*T_SEQ + t0;
#pragma unroll
    for (int p=0; p<2; p++){
        int d  = (tid>>3) + p*32;
        int c8 = (tid&7)*8;
        ushort8 v;
#pragma unroll
        for (int j=0;j<8;j++) v[j] = tile[c8+j][d];
        *(ushort8*)(dst + (size_t)d*T_SEQ + c8) = v;
    }
}

// ---------------- Flash attention (r7 numerics, one-tile-delayed PV pipeline) ----------------
// 512 thr (8 waves), 128 q rows/block (wave = 16 rows), KV tile 64, dbuf K/V^T.
// Swapped QK^T: S^T = mfma(K, Q): lane owns q-row c16, kv = n*16+g*4+r.
// Pipeline: iter t does QK(t) MFMA, then PV(t-1) MFMA (all reg operands -> fills
// matrix pipe while QK latency resolves), then softmax(t) VALU overlapping V(t)
// ds_reads into regs. PW write(t)->read(t) crosses the block barrier (visible);
// write(t+1) vs read(t) compile order pinned by sched_barrier(0) (TBAA hazard).
// Rescale at tile t is applied after PV(t-1) accumulation -> math identical to r7.
__global__ __launch_bounds__(512,4) void flash_kernel(
    const ushort_t* __restrict__ Qp, const ushort_t* __restrict__ Kp, const ushort_t* __restrict__ Vt,
    const float* __restrict__ frac, const float* __restrict__ alphap, const float* __restrict__ alphan,
    float* __restrict__ O)
{
    // XCD-aware: 2 bh per XCD slot; their K/V (2 MB) live in that XCD's L2
    int i    = blockIdx.x;
    int slot = i & 7;
    int seq  = i >> 3;                   // [0,64)
    int bh   = slot*2 + (seq >> 5);
    int qt   = seq & 31;
    int b    = bh >> 3, h = bh & 7;
    int q0   = qt * 128;

    const int tid  = threadIdx.x;
    const int w    = tid >> 6;           // [0,8)
    const int lane = tid & 63;
    const int g    = lane >> 4;
    const int c16  = lane & 15;

    __shared__ ushort_t Ks [2][64*64];   // [kv][d], chunk ^ (row&7)
    __shared__ ushort_t VTs[2][64*64];   // [d][kv], chunk ^ (row&7)
    __shared__ ushort_t PW [8][16*64];   // per-wave P^T as [q][kv], pair-swizzled

    const ushort_t* Qbase = Qp + (size_t)(b*T_SEQ)*DM + h*HD_;
    const ushort_t* Kbase = Kp + (size_t)(b*T_SEQ)*DM + h*HD_;
    const ushort_t* Vtb   = Vt + (size_t)bh*HD_*T_SEQ;
    const float*    fr    = frac + b*T_SEQ;
    const float c1 = 0.5f*(alphap[h] + alphan[h]) * LOG2E;   // bias = c1*dd + c2*|dd|
    const float c2 = 0.5f*(alphap[h] - alphan[h]) * LOG2E;   // == ap*max(dd,0)+an*min(dd,0)
    const int qrow = q0 + w*16;

    // Q fragments (B-operand: col = c16, k = ks*32 + g*8 + e)
    bf16x8 qa[2];
#pragma unroll
    for (int ks=0; ks<2; ks++)
        qa[ks] = *(const bf16x8*)(Qbase + (size_t)(qrow + c16)*DM + ks*32 + g*8);
    const float fi = fr[qrow + c16];     // this lane's q-row frac

    float m2   = -1e30f;                 // running max (log2 domain)
    float lsum = 0.f;
    f32x4 acc[4];                        // O^T: lane holds q=c16, d = dt*16+g*4+r
#pragma unroll
    for (int dt=0; dt<4; dt++) acc[dt] = (f32x4){0.f,0.f,0.f,0.f};

    bf16x8 vbp[2][4];                    // V^T frags of tile t, consumed by PV at t+1

#define STAGE(BUF, KV0)                                                          \
    {                                                                            \
        int cb  = w*64;                                                          \
        int idx = cb + lane;                                                     \
        int row = idx >> 3, cc = idx & 7;                                        \
        int cs  = cc ^ (row & 7);                                                \
        gload_lds16(Kbase + (size_t)((KV0)+row)*DM + cs*8, &Ks[BUF][cb*8]);      \
        gload_lds16(Vtb + (size_t)row*T_SEQ + (KV0) + cs*8, &VTs[BUF][cb*8]);    \
    }

    STAGE(0, 0);
    asm volatile("s_waitcnt vmcnt(0)" ::: "memory");
    __syncthreads();

    int buf = 0;
#pragma unroll 1
    for (int kt=0; kt<T_SEQ/64; kt++){
        int kv0 = kt*64;
        if (kt+1 < T_SEQ/64) STAGE(buf^1, kv0+64);

        // --- P(t-1) fragment reads (issue early; consumed by PV cluster) ---
        bf16x8 pb0, pb1;
        if (kt > 0){
            pb0 = *(const bf16x8*)&PW[w][c16*64 + (((    g) ^ (c16&7))<<3)];
            pb1 = *(const bf16x8*)&PW[w][c16*64 + (((4 + g) ^ (c16&7))<<3)];
        }

        // --- S^T = K Q^T (Q pre-scaled by 0.125*log2e) ---
        f32x4 s[4];                      // s[n][r]: kv = n*16+g*4+r, q = c16
#pragma unroll
        for (int n=0; n<4; n++) s[n] = (f32x4){0.f,0.f,0.f,0.f};
        __builtin_amdgcn_s_setprio(1);
#pragma unroll
        for (int n=0; n<4; n++){
#pragma unroll
            for (int ks=0; ks<2; ks++){
                int row = n*16 + c16;
                bf16x8 kb = *(const bf16x8*)&Ks[buf][row*64 + (((ks*4+g) ^ (row&7))<<3)];
                s[n] = MFMA_BF16(kb, qa[ks], s[n]);   // A=K, B=Q
            }
        }
        // --- PV(t-1): all operands in registers; fills MFMA pipe under QK latency ---
        if (kt > 0){
#pragma unroll
            for (int dt=0; dt<4; dt++) acc[dt] = MFMA_BF16(vbp[0][dt], pb0, acc[dt]);
#pragma unroll
            for (int dt=0; dt<4; dt++) acc[dt] = MFMA_BF16(vbp[1][dt], pb1, acc[dt]);
        }
        __builtin_amdgcn_s_setprio(0);
        // pin compile-time order: PW pack-writes below must not move above pb reads
        __builtin_amdgcn_sched_barrier(0);

        // --- bias (log2 domain, select-free algebra) ---
        float mx;
#pragma unroll
        for (int n=0; n<4; n++){
            f32x4 fj = *(const f32x4*)&fr[kv0 + n*16 + g*4];
#pragma unroll
            for (int r=0; r<4; r++){
                float dd = fj[r] - fi;
                s[n][r] = fmaf(c1, dd, fmaf(c2, fabsf(dd), s[n][r]));
            }
            float t = fmaxf(fmaxf(s[n][0], s[n][1]), fmaxf(s[n][2], s[n][3]));
            mx = (n==0) ? t : fmaxf(mx, t);
        }
        // cross-lane row max (lanes c16, c16+16, c16+32, c16+48 share q-row)
        mx = fmaxf(mx, __shfl_xor(mx, 16));
        mx = fmaxf(mx, __shfl_xor(mx, 32));

        // --- defer-max rescale (threshold 12 in log2 ~ e^8.3) ---
        // acc already includes PV(t-1) -> rescale ordering identical to r7
        if (__any(mx > m2 + 12.0f)){
            float mnew = fmaxf(m2, mx);
            float fac  = exp2_fast(m2 - mnew);
            lsum *= fac;
#pragma unroll
            for (int dt=0; dt<4; dt++)
#pragma unroll
                for (int r=0; r<4; r++) acc[dt][r] *= fac;
            m2 = mnew;
        }

        // --- exp2, row-sum, pack P -> LDS ---
        float tn[4];
#pragma unroll
        for (int n=0; n<4; n++){
#pragma unroll
            for (int r=0; r<4; r++) s[n][r] = exp2_fast(s[n][r] - m2);
            tn[n] = (s[n][0] + s[n][1]) + (s[n][2] + s[n][3]);
            unsigned pk0 = cvt_pk_bf16(s[n][0], s[n][1]);
            unsigned pk1 = cvt_pk_bf16(s[n][2], s[n][3]);
            uint2 u; u.x = pk0; u.y = pk1;
            int off = c16*64 + (((n*2 + (g>>1)) ^ (c16 & 7))<<3) + ((g&1)<<2);
            *(uint2*)&PW[w][off] = u;
        }
        float rs = (tn[0] + tn[1]) + (tn[2] + tn[3]);
        rs += __shfl_xor(rs, 16);
        rs += __shfl_xor(rs, 32);
        lsum += rs;

        // --- V(t) -> regs for next iteration's PV (VTs[buf] stable this iter) ---
#pragma unroll
        for (int ks=0; ks<2; ks++)
#pragma unroll
            for (int dt=0; dt<4; dt++){
                int vr = dt*16 + c16;
                vbp[ks][dt] = *(const bf16x8*)&VTs[buf][vr*64 + (((ks*4+g) ^ (vr&7))<<3)];
            }

        asm volatile("s_waitcnt vmcnt(0)" ::: "memory");
        __syncthreads();
        buf ^= 1;
    }
#undef STAGE

    // --- epilogue PV(T-1): PW visible (final barrier crossed) ---
    {
        bf16x8 pb0 = *(const bf16x8*)&PW[w][c16*64 + (((    g) ^ (c16&7))<<3)];
        bf16x8 pb1 = *(const bf16x8*)&PW[w][c16*64 + (((4 + g) ^ (c16&7))<<3)];
#pragma unroll
        for (int dt=0; dt<4; dt++) acc[dt] = MFMA_BF16(vbp[0][dt], pb0, acc[dt]);
#pragma unroll
        for (int dt=0; dt<4; dt++) acc[dt] = MFMA_BF16(vbp[1][dt], pb1, acc[dt]);
    }

    // --- store: O[b, qrow+c16, h*64 + dt*16 + g*4 + r] ---
    float inv = 1.0f / lsum;
    float* orow = O + (size_t)(b*T_SEQ + qrow + c16)*DM + h*HD_;
#pragma unroll
    for (int dt=0; dt<4; dt++){
        float4 o4;
        o4.x = acc[dt][0]*inv; o4.y = acc[dt][1]*inv;
        o4.z = acc[dt][2]*inv; o4.w = acc[dt][3]*inv;
        *(float4*)(orow + dt*16 + g*4) = o4;
    }
}

// ---------------- launcher ----------------
extern "C" void kernel_launch(void* const* d_in, const int* in_sizes, int n_in,
                              void* d_out, int out_size, void* d_ws, size_t ws_size,
                              hipStream_t stream)
{
    const float* q  = (const float*)d_in[0];
    const float* k  = (const float*)d_in[1];
    const float* v  = (const float*)d_in[2];
    const float* fr = (const float*)d_in[3];
    const float* Wq = (const float*)d_in[4];
    const float* bq = (const float*)d_in[5];
    const float* Wk = (const float*)d_in[6];
    const float* bk = (const float*)d_in[7];
    const float* Wv = (const float*)d_in[8];
    const float* bv = (const float*)d_in[9];
    const float* Wo = (const float*)d_in[10];
    const float* bo = (const float*)d_in[11];
    const float* ap = (const float*)d_in[12];
    const float* an = (const float*)d_in[13];

    const size_t MT = (size_t)(2*T_SEQ) * DM;              // 4M elements
    ushort_t* QKVp = (ushort_t*)d_ws;                      // Q,K,V bf16 (24 MB)
    ushort_t* Vtp  = QKVp + 3*MT;                          // V^T bf16 (8 MB)
    float*    O    = (float*)((char*)d_ws + 4*MT*sizeof(ushort_t)); // 16 MB f32

    dim3 gq(64, 4, 3);
    gemm_qkv_kernel<<<gq, 256, 0, stream>>>(q,k,v,Wq,bq,Wk,bk,Wv,bv,QKVp);

    vtrans_kernel<<<1024, 256, 0, stream>>>(QKVp + 2*MT, Vtp);

    flash_kernel<<<512, 512, 0, stream>>>(QKVp, QKVp + MT, Vtp, fr, ap, an, O);

    dim3 go(64, 4, 1);
    gemm_out_kernel<<<go, 256, 0, stream>>>(O, Wo, bo, (float*)d_out);
}

// Round 9
// 166.951 us; speedup vs baseline: 1.8289x; 1.0276x over previous
//
#include <hip/hip_runtime.h>

typedef __attribute__((ext_vector_type(8))) __bf16 bf16x8;
typedef __attribute__((ext_vector_type(8))) unsigned short ushort8;
typedef __attribute__((ext_vector_type(4))) unsigned short ushort4_t;
typedef __attribute__((ext_vector_type(4))) float f32x4;
typedef unsigned short ushort_t;

#define MFMA_BF16(A,B,C) __builtin_amdgcn_mfma_f32_16x16x32_bf16(A,B,C,0,0,0)

#define T_SEQ 4096
#define DM 512
#define HD_ 64
#define NH_ 8

#define LOG2E 1.4426950408889634f
#define QSCALE (0.125f * LOG2E)

__device__ __forceinline__ unsigned short f2b(float f){
    unsigned int u = __builtin_bit_cast(unsigned int, f);
    u += 0x7FFFu + ((u >> 16) & 1u);   // round-to-nearest-even
    return (unsigned short)(u >> 16);
}

__device__ __forceinline__ float exp2_fast(float x){
#if __has_builtin(__builtin_amdgcn_exp2f)
    return __builtin_amdgcn_exp2f(x);
#else
    float r; asm("v_exp_f32 %0, %1" : "=v"(r) : "v"(x)); return r;
#endif
}

__device__ __forceinline__ float max3f(float a, float b, float c){
    return fmaxf(fmaxf(a, b), c);      // clang fuses to v_max3_f32
}

__device__ __forceinline__ unsigned cvt_pk_bf16(float a, float b){
    unsigned r;
    asm("v_cvt_pk_bf16_f32 %0, %1, %2" : "=v"(r) : "v"(a), "v"(b));
    return r;
}

__device__ __forceinline__ void gload_lds16(const void* g, void* l){
    __builtin_amdgcn_global_load_lds((const __attribute__((address_space(1))) void*)g,
                                     (__attribute__((address_space(3))) void*)l, 16, 0, 0);
}

// ---------------- GEMM: C[M,512] = (A[M,512] @ W[512,512]^T + bias) * scale ----------------
// MODE 0: f32 row-major C. MODE 1: bf16 row-major C. MODE 2: bf16 V^T write:
//   Vt[(b*8+h)*64 + d][t] <- C[bt][col], b=bt>>12, t=bt&4095, h=col>>6, d=col&63.
template<int MODE>
__device__ __forceinline__ void gemm_body(const float* __restrict__ A, const float* __restrict__ W,
                                          const float* __restrict__ bias, void* __restrict__ Cout,
                                          int m0, int n0, float scale)
{
    constexpr int K = 512, N = 512;
    __shared__ ushort_t As[128*64];
    __shared__ ushort_t Bs[128*64];

    const int tid  = threadIdx.x;
    const int lane = tid & 63;
    const int w    = tid >> 6;
    const int g    = lane >> 4;
    const int c16  = lane & 15;
    const int wm   = w >> 1, wn = w & 1;

    f32x4 acc[4][4];
#pragma unroll
    for (int i=0;i<4;i++)
#pragma unroll
        for (int j=0;j<4;j++) acc[i][j] = (f32x4){0.f,0.f,0.f,0.f};

#pragma unroll 1
    for (int kt=0; kt<K/64; kt++){
        __syncthreads();
#pragma unroll
        for (int j=0;j<4;j++){
            int cid = j*256 + tid;
            int row = cid >> 3, ch = cid & 7;
            const float* srcA = A + (size_t)(m0+row)*K + kt*64 + ch*8;
            const float* srcB = W + (size_t)(n0+row)*K + kt*64 + ch*8;
            float4 a0 = *(const float4*)srcA;
            float4 a1 = *(const float4*)(srcA+4);
            float4 b0 = *(const float4*)srcB;
            float4 b1 = *(const float4*)(srcB+4);
            ushort8 va, vb;
            va[0]=f2b(a0.x); va[1]=f2b(a0.y); va[2]=f2b(a0.z); va[3]=f2b(a0.w);
            va[4]=f2b(a1.x); va[5]=f2b(a1.y); va[6]=f2b(a1.z); va[7]=f2b(a1.w);
            vb[0]=f2b(b0.x); vb[1]=f2b(b0.y); vb[2]=f2b(b0.z); vb[3]=f2b(b0.w);
            vb[4]=f2b(b1.x); vb[5]=f2b(b1.y); vb[6]=f2b(b1.z); vb[7]=f2b(b1.w);
            int dst = row*64 + ((ch ^ (row & 7))<<3);
            *(ushort8*)&As[dst] = va;
            *(ushort8*)&Bs[dst] = vb;
        }
        __syncthreads();
#pragma unroll
        for (int ks=0; ks<2; ks++){
            bf16x8 af[4], bfr[4];
#pragma unroll
            for (int f=0; f<4; f++){
                int rowa = wm*64 + f*16 + c16;
                af[f]  = *(const bf16x8*)&As[rowa*64 + (((ks*4+g) ^ (rowa&7))<<3)];
                int rowb = wn*64 + f*16 + c16;
                bfr[f] = *(const bf16x8*)&Bs[rowb*64 + (((ks*4+g) ^ (rowb&7))<<3)];
            }
#pragma unroll
            for (int fm=0; fm<4; fm++)
#pragma unroll
                for (int fn=0; fn<4; fn++)
                    acc[fm][fn] = MFMA_BF16(af[fm], bfr[fn], acc[fm][fn]);
        }
    }
#pragma unroll
    for (int fm=0; fm<4; fm++)
#pragma unroll
        for (int fn=0; fn<4; fn++){
            int col = n0 + wn*64 + fn*16 + c16;
            float bv = bias[col];
            if (MODE == 2){
                // transposed V^T store: 4 consecutive t at fixed d -> 8B store
                int t0r = m0 + wm*64 + fm*16 + g*4;          // 4-aligned
                int b2  = t0r >> 12;                          // tile never crosses b
                int t   = t0r & 4095;
                int h2  = col >> 6, d = col & 63;
                ushort4_t u;
#pragma unroll
                for (int r=0; r<4; r++) u[r] = f2b(acc[fm][fn][r] + bv);
                ushort_t* dst = (ushort_t*)Cout + ((size_t)(b2*NH_ + h2)*HD_ + d)*T_SEQ + t;
                *(ushort4_t*)dst = u;
            } else {
#pragma unroll
                for (int r=0; r<4; r++){
                    int rowm = m0 + wm*64 + fm*16 + g*4 + r;
                    float vv = (acc[fm][fn][r] + bv) * scale;
                    if (MODE == 1) ((ushort_t*)Cout)[(size_t)rowm*N + col] = f2b(vv);
                    else           ((float*)Cout)[(size_t)rowm*N + col]   = vv;
                }
            }
        }
}

__global__ __launch_bounds__(256,2) void gemm_qkv_kernel(
    const float* __restrict__ q, const float* __restrict__ k, const float* __restrict__ v,
    const float* __restrict__ Wq, const float* __restrict__ bq,
    const float* __restrict__ Wk, const float* __restrict__ bk,
    const float* __restrict__ Wv, const float* __restrict__ bv,
    ushort_t* __restrict__ QKVp)
{
    int z = blockIdx.z;
    const float* A  = (z==0) ? q  : (z==1 ? k  : v);
    const float* W  = (z==0) ? Wq : (z==1 ? Wk : Wv);
    const float* bb = (z==0) ? bq : (z==1 ? bk : bv);
    ushort_t* C = QKVp + (size_t)z * (size_t)(2*T_SEQ) * DM;
    if (z == 2)
        gemm_body<2>(A, W, bb, C, blockIdx.x*128, blockIdx.y*128, 1.0f);   // V^T direct
    else
        gemm_body<1>(A, W, bb, C, blockIdx.x*128, blockIdx.y*128,
                     (z==0) ? QSCALE : 1.0f);                               // bake 0.125*log2e into Q
}

__global__ __launch_bounds__(256,2) void gemm_out_kernel(
    const float* __restrict__ O, const float* __restrict__ Wo,
    const float* __restrict__ bo, float* __restrict__ out)
{
    gemm_body<0>(O, Wo, bo, out, blockIdx.x*128, blockIdx.y*128, 1.0f);
}

// ---------------- Flash attention (r8 pipeline + ones-MFMA lsum) ----------------
// 512 thr (8 waves), 128 q rows/block (wave = 16 rows), KV tile 64, dbuf K/V^T.
// Swapped QK^T: S^T = mfma(K, Q): lane owns q-row c16, kv = n*16+g*4+r.
// One-tile-delayed PV; lsum = ones-MFMA column-sums of the SAME pb that PV uses
// (denominator == sum of numerator weights; cannot diverge from PV).
__global__ __launch_bounds__(512,4) void flash_kernel(
    const ushort_t* __restrict__ Qp, const ushort_t* __restrict__ Kp, const ushort_t* __restrict__ Vt,
    const float* __restrict__ frac, const float* __restrict__ alphap, const float* __restrict__ alphan,
    float* __restrict__ O)
{
    // XCD-aware: 2 bh per XCD slot; their K/V (2 MB) live in that XCD's L2
    int i    = blockIdx.x;
    int slot = i & 7;
    int seq  = i >> 3;                   // [0,64)
    int bh   = slot*2 + (seq >> 5);
    int qt   = seq & 31;
    int b    = bh >> 3, h = bh & 7;
    int q0   = qt * 128;

    const int tid  = threadIdx.x;
    const int w    = tid >> 6;           // [0,8)
    const int lane = tid & 63;
    const int g    = lane >> 4;
    const int c16  = lane & 15;

    __shared__ ushort_t Ks [2][64*64];   // [kv][d], chunk ^ (row&7)
    __shared__ ushort_t VTs[2][64*64];   // [d][kv], chunk ^ (row&7)
    __shared__ ushort_t PW [8][16*64];   // per-wave P^T as [q][kv], pair-swizzled

    const ushort_t* Qbase = Qp + (size_t)(b*T_SEQ)*DM + h*HD_;
    const ushort_t* Kbase = Kp + (size_t)(b*T_SEQ)*DM + h*HD_;
    const ushort_t* Vtb   = Vt + (size_t)bh*HD_*T_SEQ;
    const float*    fr    = frac + b*T_SEQ;
    const float c1 = 0.5f*(alphap[h] + alphan[h]) * LOG2E;   // bias = c1*dd + c2*|dd|
    const float c2 = 0.5f*(alphap[h] - alphan[h]) * LOG2E;   // == ap*max(dd,0)+an*min(dd,0)
    const int qrow = q0 + w*16;

    // Q fragments (B-operand: col = c16, k = ks*32 + g*8 + e)
    bf16x8 qa[2];
#pragma unroll
    for (int ks=0; ks<2; ks++)
        qa[ks] = *(const bf16x8*)(Qbase + (size_t)(qrow + c16)*DM + ks*32 + g*8);
    const float fi = fr[qrow + c16];     // this lane's q-row frac

    // ones vector for the lsum MFMA
    ushort8 ou;
#pragma unroll
    for (int j=0;j<8;j++) ou[j] = 0x3F80;
    const bf16x8 ones = __builtin_bit_cast(bf16x8, ou);

    float m2 = -1e30f;                   // running max (log2 domain)
    f32x4 acc[4];                        // O^T: lane holds q=c16, d = dt*16+g*4+r
    f32x4 asum;                          // row-sum accumulator (all regs equal)
#pragma unroll
    for (int dt=0; dt<4; dt++) acc[dt] = (f32x4){0.f,0.f,0.f,0.f};
    asum = (f32x4){0.f,0.f,0.f,0.f};

    bf16x8 vbp[2][4];                    // V^T frags of tile t, consumed by PV at t+1

#define STAGE(BUF, KV0)                                                          \
    {                                                                            \
        int cb  = w*64;                                                          \
        int idx = cb + lane;                                                     \
        int row = idx >> 3, cc = idx & 7;                                        \
        int cs  = cc ^ (row & 7);                                                \
        gload_lds16(Kbase + (size_t)((KV0)+row)*DM + cs*8, &Ks[BUF][cb*8]);      \
        gload_lds16(Vtb + (size_t)row*T_SEQ + (KV0) + cs*8, &VTs[BUF][cb*8]);    \
    }

    STAGE(0, 0);
    asm volatile("s_waitcnt vmcnt(0)" ::: "memory");
    __syncthreads();

    int buf = 0;
#pragma unroll 1
    for (int kt=0; kt<T_SEQ/64; kt++){
        int kv0 = kt*64;
        if (kt+1 < T_SEQ/64) STAGE(buf^1, kv0+64);

        // --- P(t-1) fragment reads (issue early; consumed by PV cluster) ---
        bf16x8 pb0, pb1;
        if (kt > 0){
            pb0 = *(const bf16x8*)&PW[w][c16*64 + (((    g) ^ (c16&7))<<3)];
            pb1 = *(const bf16x8*)&PW[w][c16*64 + (((4 + g) ^ (c16&7))<<3)];
        }

        // --- S^T = K Q^T (Q pre-scaled by 0.125*log2e) ---
        f32x4 s[4];                      // s[n][r]: kv = n*16+g*4+r, q = c16
#pragma unroll
        for (int n=0; n<4; n++) s[n] = (f32x4){0.f,0.f,0.f,0.f};
        __builtin_amdgcn_s_setprio(1);
#pragma unroll
        for (int n=0; n<4; n++){
#pragma unroll
            for (int ks=0; ks<2; ks++){
                int row = n*16 + c16;
                bf16x8 kb = *(const bf16x8*)&Ks[buf][row*64 + (((ks*4+g) ^ (row&7))<<3)];
                s[n] = MFMA_BF16(kb, qa[ks], s[n]);   // A=K, B=Q
            }
        }
        // --- PV(t-1) + lsum(t-1): all operands in registers ---
        if (kt > 0){
            asum = MFMA_BF16(ones, pb0, asum);
#pragma unroll
            for (int dt=0; dt<4; dt++) acc[dt] = MFMA_BF16(vbp[0][dt], pb0, acc[dt]);
            asum = MFMA_BF16(ones, pb1, asum);
#pragma unroll
            for (int dt=0; dt<4; dt++) acc[dt] = MFMA_BF16(vbp[1][dt], pb1, acc[dt]);
        }
        __builtin_amdgcn_s_setprio(0);
        // pin compile-time order: PW pack-writes below must not move above pb reads
        __builtin_amdgcn_sched_barrier(0);

        // --- bias (log2 domain, select-free algebra) ---
#pragma unroll
        for (int n=0; n<4; n++){
            f32x4 fj = *(const f32x4*)&fr[kv0 + n*16 + g*4];
#pragma unroll
            for (int r=0; r<4; r++){
                float dd = fj[r] - fi;
                s[n][r] = fmaf(c1, dd, fmaf(c2, fabsf(dd), s[n][r]));
            }
        }
        // in-lane max via max3 trees, then cross-lane (4 lanes share a q-row)
        float mx;
        {
            float t0 = max3f(s[0][0], s[0][1], s[0][2]);
            float t1 = max3f(s[0][3], s[1][0], s[1][1]);
            float t2 = max3f(s[1][2], s[1][3], s[2][0]);
            float t3 = max3f(s[2][1], s[2][2], s[2][3]);
            float t4 = max3f(s[3][0], s[3][1], s[3][2]);
            mx = fmaxf(max3f(t0, t1, t2), max3f(t3, t4, s[3][3]));
        }
        mx = fmaxf(mx, __shfl_xor(mx, 16));
        mx = fmaxf(mx, __shfl_xor(mx, 32));

        // --- defer-max rescale (threshold 12 in log2 ~ e^8.3) ---
        // acc/asum already include PV(t-1) -> ordering identical to r7/r8
        if (__any(mx > m2 + 12.0f)){
            float mnew = fmaxf(m2, mx);
            float fac  = exp2_fast(m2 - mnew);
#pragma unroll
            for (int r=0; r<4; r++) asum[r] *= fac;
#pragma unroll
            for (int dt=0; dt<4; dt++)
#pragma unroll
                for (int r=0; r<4; r++) acc[dt][r] *= fac;
            m2 = mnew;
        }

        // --- exp2, pack P -> LDS ---
#pragma unroll
        for (int n=0; n<4; n++){
#pragma unroll
            for (int r=0; r<4; r++) s[n][r] = exp2_fast(s[n][r] - m2);
            unsigned pk0 = cvt_pk_bf16(s[n][0], s[n][1]);
            unsigned pk1 = cvt_pk_bf16(s[n][2], s[n][3]);
            uint2 u; u.x = pk0; u.y = pk1;
            int off = c16*64 + (((n*2 + (g>>1)) ^ (c16 & 7))<<3) + ((g&1)<<2);
            *(uint2*)&PW[w][off] = u;
        }

        // --- V(t) -> regs for next iteration's PV (VTs[buf] stable this iter) ---
#pragma unroll
        for (int ks=0; ks<2; ks++)
#pragma unroll
            for (int dt=0; dt<4; dt++){
                int vr = dt*16 + c16;
                vbp[ks][dt] = *(const bf16x8*)&VTs[buf][vr*64 + (((ks*4+g) ^ (vr&7))<<3)];
            }

        asm volatile("s_waitcnt vmcnt(0)" ::: "memory");
        __syncthreads();
        buf ^= 1;
    }
#undef STAGE

    // --- epilogue PV(T-1): PW visible (final barrier crossed) ---
    {
        bf16x8 pb0 = *(const bf16x8*)&PW[w][c16*64 + (((    g) ^ (c16&7))<<3)];
        bf16x8 pb1 = *(const bf16x8*)&PW[w][c16*64 + (((4 + g) ^ (c16&7))<<3)];
        asum = MFMA_BF16(ones, pb0, asum);
#pragma unroll
        for (int dt=0; dt<4; dt++) acc[dt] = MFMA_BF16(vbp[0][dt], pb0, acc[dt]);
        asum = MFMA_BF16(ones, pb1, asum);
#pragma unroll
        for (int dt=0; dt<4; dt++) acc[dt] = MFMA_BF16(vbp[1][dt], pb1, acc[dt]);
    }

    // --- store: O[b, qrow+c16, h*64 + dt*16 + g*4 + r] ---
    float inv = 1.0f / asum[0];
    float* orow = O + (size_t)(b*T_SEQ + qrow + c16)*DM + h*HD_;
#pragma unroll
    for (int dt=0; dt<4; dt++){
        float4 o4;
        o4.x = acc[dt][0]*inv; o4.y = acc[dt][1]*inv;
        o4.z = acc[dt][2]*inv; o4.w = acc[dt][3]*inv;
        *(float4*)(orow + dt*16 + g*4) = o4;
    }
}

// ---------------- launcher ----------------
extern "C" void kernel_launch(void* const* d_in, const int* in_sizes, int n_in,
                              void* d_out, int out_size, void* d_ws, size_t ws_size,
                              hipStream_t stream)
{
    const float* q  = (const float*)d_in[0];
    const float* k  = (const float*)d_in[1];
    const float* v  = (const float*)d_in[2];
    const float* fr = (const float*)d_in[3];
    const float* Wq = (const float*)d_in[4];
    const float* bq = (const float*)d_in[5];
    const float* Wk = (const float*)d_in[6];
    const float* bk = (const float*)d_in[7];
    const float* Wv = (const float*)d_in[8];
    const float* bv = (const float*)d_in[9];
    const float* Wo = (const float*)d_in[10];
    const float* bo = (const float*)d_in[11];
    const float* ap = (const float*)d_in[12];
    const float* an = (const float*)d_in[13];

    const size_t MT = (size_t)(2*T_SEQ) * DM;              // 4M elements
    ushort_t* QKVp = (ushort_t*)d_ws;                      // Q, K, V^T bf16 (24 MB)
    float*    O    = (float*)((char*)d_ws + 3*MT*sizeof(ushort_t)); // 16 MB f32

    dim3 gq(64, 4, 3);
    gemm_qkv_kernel<<<gq, 256, 0, stream>>>(q,k,v,Wq,bq,Wk,bk,Wv,bv,QKVp);

    flash_kernel<<<512, 512, 0, stream>>>(QKVp, QKVp + MT, QKVp + 2*MT, fr, ap, an, O);

    dim3 go(64, 4, 1);
    gemm_out_kernel<<<go, 256, 0, stream>>>(O, Wo, bo, (float*)d_out);
}